// Round 13
// baseline (50.818 us; speedup 1.0000x reference)
//
#include <hip/hip_runtime.h>

#define H   768
#define Hh  384
#define LL  192
#define RR  24
#define HH  589824   // 768*768

typedef __attribute__((ext_vector_type(8))) short bf16x8;
typedef __attribute__((ext_vector_type(4))) float f32x4;

__device__ __forceinline__ unsigned short f2bf(float f) {
    unsigned int u = __float_as_uint(f);
    return (unsigned short)((u + 0x7FFF + ((u >> 16) & 1)) >> 16);  // RNE
}

__device__ __forceinline__ float wred(float v) {
#pragma unroll
    for (int off = 1; off < 64; off <<= 1) v += __shfl_xor(v, off);
    return v;
}

// ---------------------------------------------------------------------------
// kA: grid 673 x 256
//   [0,288)   : bf16 MFMA GEMM 64x64, BK=64; A/B read fp32 + in-reg cvt,
//               T14 split pipeline (load k+2 / write k+1 / mfma k)
//               sel 0: hfb = emb@W_corr[:H] (+b_corr), 1: hsb = emb@W_corr[H:]
//   [288,480) : relh partials (k-split x8), avg slice computed inline
//   [480,672) : W8/V8 build (wave per k)
//   672       : cb + bc
// ---------------------------------------------------------------------------
__global__ __launch_bounds__(256) void k_A(
    const float* __restrict__ emb, const int* __restrict__ mask,
    const float* __restrict__ W_corr, const float* __restrict__ W_tag,
    const float* __restrict__ W_gc, const float* __restrict__ W_relh,
    const float* __restrict__ W_sub, const float* __restrict__ b_sub,
    const float* __restrict__ W_obj, const float* __restrict__ b_obj,
    const float* __restrict__ b_tag, const float* __restrict__ b_corr,
    float* __restrict__ hfb, float* __restrict__ hsb,
    float* __restrict__ relh_part,
    float* __restrict__ W8_ws, float* __restrict__ V8_ws,
    float* __restrict__ cb_ws, float* __restrict__ bc_ws)
{
    __shared__ unsigned short As[2][4096];
    __shared__ unsigned short Bs[2][4096];
    const int bid = blockIdx.x, tid = threadIdx.x;

    if (bid >= 288) {
        if (bid < 480) {
            // ---- relh partials, avg slice inline ----
            float* sp   = (float*)&As[0][0];
            float* msk  = sp;            // 192
            float* red2 = sp + 192;      // 192
            float* avgS = sp + 384;      // 96
            float* msum = sp + 480;      // 1
            float* red  = sp + 512;      // 256
            const int rb = bid - 288;
            const int kc = rb & 7;
            const int t2 = rb >> 3;
            const int b  = t2 / 6;
            const int o0 = (t2 % 6) * 64;
            if (tid < 192) msk[tid] = (float)mask[b * LL + tid];
            __syncthreads();
            if (tid < 64) {
                float s = msk[tid] + msk[64 + tid] + msk[128 + tid];
                s = wred(s);
                if (tid == 0) msum[0] = s;
            }
            if (tid < 192) {
                const int h  = tid % 96;
                const int lh = tid / 96;
                float s = 0.f;
                for (int i = 0; i < 96; ++i) {
                    const int l = lh * 96 + i;
                    s += msk[l] * emb[(size_t)(b * LL + l) * H + kc * 96 + h];
                }
                red2[lh * 96 + h] = s;
            }
            __syncthreads();
            if (tid < 96)
                avgS[tid] = (red2[tid] + red2[96 + tid]) / msum[0];
            __syncthreads();
            const int tx = tid & 63, ty = tid >> 6;
            float s = 0.f;
            for (int hh = 0; hh < 24; ++hh)
                s += avgS[ty * 24 + hh] *
                     W_relh[(size_t)(kc * 96 + ty * 24 + hh) * Hh + o0 + tx];
            red[ty * 64 + tx] = s;
            __syncthreads();
            if (ty == 0)
                relh_part[(size_t)(kc * 4 + b) * Hh + o0 + tx] =
                    red[tx] + red[64 + tx] + red[128 + tx] + red[192 + tx];
        } else if (bid < 672) {
            // ---- W8/V8 build: wave per k ----
            const int wave = tid >> 6, lane = tid & 63;
            const int k = (bid - 480) * 4 + wave;
            const float* rc0 = W_corr + (size_t)k * H;
            const float* rc1 = W_corr + (size_t)HH + (size_t)k * H;
            const float* rtl = W_tag + (size_t)k * H;
            const float* rth = W_tag + (size_t)(H + k) * H;
            float u0 = 0.f, u1 = 0.f;
            float wsv[3] = {0, 0, 0}, wov[3] = {0, 0, 0};
            float vsv[3] = {0, 0, 0}, vov[3] = {0, 0, 0};
#pragma unroll
            for (int it = 0; it < 3; ++it) {
                const int h = lane * 4 + it * 256;
                const float4 c0 = *(const float4*)(rc0 + h);
                const float4 c1 = *(const float4*)(rc1 + h);
                const float4 tl = *(const float4*)(rtl + h);
                const float4 th = *(const float4*)(rth + h);
                const float4 g  = *(const float4*)(W_gc + h);
                float su[12], ob[12];
                *(float4*)&su[0] = *(const float4*)(W_sub + h * 3);
                *(float4*)&su[4] = *(const float4*)(W_sub + h * 3 + 4);
                *(float4*)&su[8] = *(const float4*)(W_sub + h * 3 + 8);
                *(float4*)&ob[0] = *(const float4*)(W_obj + h * 3);
                *(float4*)&ob[4] = *(const float4*)(W_obj + h * 3 + 4);
                *(float4*)&ob[8] = *(const float4*)(W_obj + h * 3 + 8);
                u0 += c0.x * g.x + c0.y * g.y + c0.z * g.z + c0.w * g.w;
                u1 += c1.x * g.x + c1.y * g.y + c1.z * g.z + c1.w * g.w;
                const float t4[4] = {th.x, th.y, th.z, th.w};
                const float l4[4] = {tl.x, tl.y, tl.z, tl.w};
#pragma unroll
                for (int d = 0; d < 4; ++d)
#pragma unroll
                    for (int c = 0; c < 3; ++c) {
                        wsv[c] += t4[d] * su[d * 3 + c];
                        vsv[c] += l4[d] * su[d * 3 + c];
                        wov[c] += t4[d] * ob[d * 3 + c];
                        vov[c] += l4[d] * ob[d * 3 + c];
                    }
            }
            u0 = wred(u0); u1 = wred(u1);
#pragma unroll
            for (int c = 0; c < 3; ++c) {
                wsv[c] = wred(wsv[c]); wov[c] = wred(wov[c]);
                vsv[c] = wred(vsv[c]); vov[c] = wred(vov[c]);
            }
            if (lane == 0) {
                *(float4*)(W8_ws + k * 8)     = make_float4(u0, u1, wsv[0], wsv[1]);
                *(float4*)(W8_ws + k * 8 + 4) = make_float4(wsv[2], wov[0], wov[1], wov[2]);
                *(float4*)(V8_ws + k * 8)     = make_float4(vsv[0], vsv[1], vsv[2], vov[0]);
                *(float4*)(V8_ws + k * 8 + 4) = make_float4(vov[1], vov[2], 0.f, 0.f);
            }
        } else {
            // ---- cb + bc ----
            const int wave = tid >> 6, lane = tid & 63;
            if (wave == 0) {
                float cs[3] = {0, 0, 0}, co[3] = {0, 0, 0};
#pragma unroll
                for (int it = 0; it < 3; ++it) {
                    const int h = lane * 4 + it * 256;
                    const float4 bt = *(const float4*)(b_tag + h);
                    float su[12], ob[12];
                    *(float4*)&su[0] = *(const float4*)(W_sub + h * 3);
                    *(float4*)&su[4] = *(const float4*)(W_sub + h * 3 + 4);
                    *(float4*)&su[8] = *(const float4*)(W_sub + h * 3 + 8);
                    *(float4*)&ob[0] = *(const float4*)(W_obj + h * 3);
                    *(float4*)&ob[4] = *(const float4*)(W_obj + h * 3 + 4);
                    *(float4*)&ob[8] = *(const float4*)(W_obj + h * 3 + 8);
                    const float b4[4] = {bt.x, bt.y, bt.z, bt.w};
#pragma unroll
                    for (int d = 0; d < 4; ++d)
#pragma unroll
                        for (int c = 0; c < 3; ++c) {
                            cs[c] += b4[d] * su[d * 3 + c];
                            co[c] += b4[d] * ob[d * 3 + c];
                        }
                }
#pragma unroll
                for (int c = 0; c < 3; ++c) { cs[c] = wred(cs[c]); co[c] = wred(co[c]); }
                if (lane == 0) {
#pragma unroll
                    for (int c = 0; c < 3; ++c) {
                        cb_ws[c]     = cs[c] + b_sub[c];
                        cb_ws[3 + c] = co[c] + b_obj[c];
                    }
                }
            } else if (wave == 1) {
                float s = 0.f;
#pragma unroll
                for (int it = 0; it < 3; ++it) {
                    const int h = lane * 4 + it * 256;
                    const float4 bcv = *(const float4*)(b_corr + h);
                    const float4 g   = *(const float4*)(W_gc + h);
                    s += bcv.x * g.x + bcv.y * g.y + bcv.z * g.z + bcv.w * g.w;
                }
                s = wred(s);
                if (lane == 0) bc_ws[0] = s;
            }
        }
        return;
    }

    // ------------------ MFMA GEMM, in-reg fp32->bf16 staging ------------------
    const int sel = bid / 144;
    const int tt  = bid % 144;
    const int mt = tt % 12, nt = tt / 12;
    const int m0 = mt * 64, n0 = nt * 64;
    const float* Bsrc = W_corr + (size_t)sel * HH;   // [k][n] fp32
    float* C = sel ? hsb : hfb;

    const int wv = tid >> 6, ln = tid & 63;
    const int lr = ln & 15, ko = ln >> 4;
    const int wr = (wv >> 1) * 32, wc = (wv & 1) * 32;

    const int am = tid >> 2, akq = tid & 3;    // A: row, 16-k group
    const int bk4 = tid >> 4, bn4 = tid & 15;  // B: 4-k group, n-quad

    float4 ra[4], rb[4];
    auto loadA = [&](int k0) {
        const float* src = emb + (size_t)(m0 + am) * H + k0 + akq * 16;
#pragma unroll
        for (int q = 0; q < 4; ++q) ra[q] = *(const float4*)(src + q * 4);
    };
    auto loadB = [&](int k0) {
        const float* src = Bsrc + (size_t)(k0 + bk4 * 4) * H + n0 + bn4 * 4;
#pragma unroll
        for (int q = 0; q < 4; ++q) rb[q] = *(const float4*)(src + (size_t)q * H);
    };
    auto writeAB = [&](int buf) {
        unsigned short t16[16];
#pragma unroll
        for (int q = 0; q < 4; ++q) {
            t16[q * 4 + 0] = f2bf(ra[q].x); t16[q * 4 + 1] = f2bf(ra[q].y);
            t16[q * 4 + 2] = f2bf(ra[q].z); t16[q * 4 + 3] = f2bf(ra[q].w);
        }
#pragma unroll
        for (int j = 0; j < 2; ++j)
            *(uint4*)(&As[buf][am * 64 + (((akq * 2 + j) ^ (am & 7)) * 8)]) =
                *(uint4*)(&t16[j * 8]);
#pragma unroll
        for (int ni = 0; ni < 4; ++ni) {
            const int n = bn4 * 4 + ni;
            unsigned long long pk =
                  (unsigned long long)f2bf((&rb[0].x)[ni])
                | ((unsigned long long)f2bf((&rb[1].x)[ni]) << 16)
                | ((unsigned long long)f2bf((&rb[2].x)[ni]) << 32)
                | ((unsigned long long)f2bf((&rb[3].x)[ni]) << 48);
            *(unsigned long long*)(&Bs[buf][n * 64 + ((bk4 >> 1) ^ (n & 7)) * 8
                                            + (bk4 & 1) * 4]) = pk;
        }
    };

    f32x4 acc[2][2];
#pragma unroll
    for (int mi = 0; mi < 2; ++mi)
#pragma unroll
        for (int ni = 0; ni < 2; ++ni)
            acc[mi][ni] = (f32x4){0.f, 0.f, 0.f, 0.f};

    loadA(0); loadB(0);
    writeAB(0);
    loadA(64); loadB(64);
    int cur = 0;
    for (int ks = 0; ks < 12; ++ks) {
        __syncthreads();
        if (ks < 11) {
            writeAB(cur ^ 1);                       // regs hold tile ks+1
            if (ks < 10) { loadA((ks + 2) * 64); loadB((ks + 2) * 64); }
        }
        bf16x8 af[2][2], bfr[2][2];
#pragma unroll
        for (int mi = 0; mi < 2; ++mi) {
            const int r = wr + mi * 16 + lr;
#pragma unroll
            for (int kc = 0; kc < 2; ++kc) {
                const int qs = (kc * 4 + ko) ^ (r & 7);
                af[kc][mi] = *(const bf16x8*)(&As[cur][r * 64 + qs * 8]);
            }
        }
#pragma unroll
        for (int ni = 0; ni < 2; ++ni) {
            const int r = wc + ni * 16 + lr;
#pragma unroll
            for (int kc = 0; kc < 2; ++kc) {
                const int qs = (kc * 4 + ko) ^ (r & 7);
                bfr[kc][ni] = *(const bf16x8*)(&Bs[cur][r * 64 + qs * 8]);
            }
        }
#pragma unroll
        for (int kc = 0; kc < 2; ++kc)
#pragma unroll
            for (int mi = 0; mi < 2; ++mi)
#pragma unroll
                for (int ni = 0; ni < 2; ++ni)
                    acc[mi][ni] = __builtin_amdgcn_mfma_f32_16x16x32_bf16(
                        af[kc][mi], bfr[kc][ni], acc[mi][ni], 0, 0, 0);
        cur ^= 1;
    }

    float cbv[2];
#pragma unroll
    for (int ni = 0; ni < 2; ++ni)
        cbv[ni] = (sel == 0) ? b_corr[n0 + wc + ni * 16 + lr] : 0.f;
#pragma unroll
    for (int mi = 0; mi < 2; ++mi)
#pragma unroll
        for (int ni = 0; ni < 2; ++ni) {
            const int m = m0 + wr + mi * 16 + ko * 4;
            const int n = n0 + wc + ni * 16 + lr;
#pragma unroll
            for (int rr = 0; rr < 4; ++rr)
                C[(size_t)(m + rr) * H + n] = acc[mi][ni][rr] + cbv[ni];
        }
}

// ---------------------------------------------------------------------------
// kB: grid 769 x 256
//   [0,576)  : corres abs-partials, 64i x 32j, h-split 8 (R12 structure)
//   [576,768): row-dots: hfw/hsw = emb.u0/u1 -> hfw_ws; raw tag dots -> traw
//   768      : tb[b][0..5] = rel_e . V8 + cb  -> tb_ws
// ---------------------------------------------------------------------------
__global__ __launch_bounds__(256) void k_B(
    const float* __restrict__ hfb, const float* __restrict__ hsb,
    const float* __restrict__ emb, const float* __restrict__ W8_ws,
    const float* __restrict__ V8_ws, const float* __restrict__ cb_ws,
    const int* __restrict__ target_rel, const float* __restrict__ rel_emb,
    const float* __restrict__ W_gc,
    float* __restrict__ cpart, float* __restrict__ hfw_ws,
    float* __restrict__ traw, float* __restrict__ tb_ws)
{
    __shared__ float hfT[96][34];   // 13 KB
    const int bid = blockIdx.x, tid = threadIdx.x;

    if (bid < 576) {
        const int s    = bid & 7;
        const int tile = bid >> 3;
        const int b   = tile / 18;
        const int rem = tile % 18;
        const int i0  = (rem / 6) * 64;
        const int j0  = (rem % 6) * 32;
        const int h0  = s * 96;
        const int tx = tid & 15, ty = tid >> 4;

#pragma unroll
        for (int it = 0; it < 3; ++it) {
            const int j = tid >> 3, q = tid & 7;
            const int k = it * 32 + q * 4;
            const float4 fv = *(const float4*)(hfb + (size_t)(b * LL + j0 + j) * H + h0 + k);
            hfT[k + 0][j] = fv.x;
            hfT[k + 1][j] = fv.y;
            hfT[k + 2][j] = fv.z;
            hfT[k + 3][j] = fv.w;
        }
        __syncthreads();

        float acc[4][2] = {{0.f}};
        float hsr[4][8];
        const float* hsbase = hsb + (size_t)(b * LL + i0 + ty * 4) * H + h0;

        for (int kb = 0; kb < 96; kb += 8) {
#pragma unroll
            for (int ii = 0; ii < 4; ++ii) {
                const float4 v0 = *(const float4*)(hsbase + (size_t)ii * H + kb);
                const float4 v1 = *(const float4*)(hsbase + (size_t)ii * H + kb + 4);
                hsr[ii][0] = v0.x; hsr[ii][1] = v0.y; hsr[ii][2] = v0.z; hsr[ii][3] = v0.w;
                hsr[ii][4] = v1.x; hsr[ii][5] = v1.y; hsr[ii][6] = v1.z; hsr[ii][7] = v1.w;
            }
            const float4 wa = *(const float4*)(W_gc + h0 + kb);
            const float4 wb = *(const float4*)(W_gc + h0 + kb + 4);
            const float wreg[8] = {wa.x, wa.y, wa.z, wa.w, wb.x, wb.y, wb.z, wb.w};
#pragma unroll
            for (int k8 = 0; k8 < 8; ++k8) {
                const int kk = kb + k8;
                const float2 f2 = *(const float2*)&hfT[kk][tx * 2];
                const float w = wreg[k8];
#pragma unroll
                for (int ii = 0; ii < 4; ++ii) {
                    acc[ii][0] += fabsf(f2.x + hsr[ii][k8]) * w;
                    acc[ii][1] += fabsf(f2.y + hsr[ii][k8]) * w;
                }
            }
        }
#pragma unroll
        for (int ii = 0; ii < 4; ++ii) {
            *(float2*)(cpart + (size_t)s * 147456 + (size_t)b * 36864
                       + (size_t)(i0 + ty * 4 + ii) * LL + j0 + tx * 2) =
                make_float2(acc[ii][0], acc[ii][1]);
        }
    } else if (bid < 768) {
        // ---- row-dots: wave per emb row; raw tag sums to traw ----
        const int wave = tid >> 6, lane = tid & 63;
        const int r = (bid - 576) * 4 + wave;
        const float* er = emb + (size_t)r * H;
        float s0 = 0.f, s1 = 0.f;
        float t[6] = {0, 0, 0, 0, 0, 0};
#pragma unroll
        for (int it = 0; it < 12; ++it) {
            const int h = lane + it * 64;
            const float e = er[h];
            const float4 a = *(const float4*)(W8_ws + h * 8);
            const float4 v = *(const float4*)(W8_ws + h * 8 + 4);
            s0 += e * a.x; s1 += e * a.y;
            t[0] += e * a.z; t[1] += e * a.w; t[2] += e * v.x;
            t[3] += e * v.y; t[4] += e * v.z; t[5] += e * v.w;
        }
        s0 = wred(s0); s1 = wred(s1);
#pragma unroll
        for (int c = 0; c < 6; ++c) t[c] = wred(t[c]);
        if (lane == 0) {
            hfw_ws[r] = s0;
            hfw_ws[768 + r] = s1;
#pragma unroll
            for (int c = 0; c < 6; ++c) traw[r * 6 + c] = t[c];
        }
    } else {
        // ---- tb: wave per batch ----
        const int b = tid >> 6, lane = tid & 63;
        const float* re = rel_emb + (size_t)target_rel[b] * H;
        float t[6] = {0, 0, 0, 0, 0, 0};
#pragma unroll
        for (int it = 0; it < 12; ++it) {
            const int k = lane + it * 64;
            const float rl = re[k];
            const float4 a = *(const float4*)(V8_ws + k * 8);
            const float4 v = *(const float4*)(V8_ws + k * 8 + 4);
            t[0] += rl * a.x; t[1] += rl * a.y; t[2] += rl * a.z;
            t[3] += rl * a.w; t[4] += rl * v.x; t[5] += rl * v.y;
        }
#pragma unroll
        for (int c = 0; c < 6; ++c) t[c] = wred(t[c]);
        if (lane == 0) {
#pragma unroll
            for (int c = 0; c < 6; ++c)
                tb_ws[b * 8 + c] = t[c] + cb_ws[c];
        }
    }
}

// ---------------------------------------------------------------------------
// kC: grid 163 x 256
//   [0,144)  : corres merge
//   [144,162): tag finalize: out = traw + tb
//   162      : relh reduce + stage1 GEMV
// ---------------------------------------------------------------------------
__global__ __launch_bounds__(256) void k_C(
    const float* __restrict__ cpart, const float* __restrict__ hfw_ws,
    const float* __restrict__ traw, const float* __restrict__ tb_ws,
    const float* __restrict__ bc_ws, const float* __restrict__ relh_part,
    const float* __restrict__ b_relh, const float* __restrict__ W_rj,
    const float* __restrict__ b_rj, const float* __restrict__ b_gc,
    float* __restrict__ out)
{
    __shared__ float pool[1536];
    const int bid = blockIdx.x, tid = threadIdx.x;

    if (bid < 144) {
        const int idx = bid * 256 + tid;
        const int b  = idx / 9216;
        const int rr = idx % 9216;
        const int i  = rr / 48;
        const int j4 = (rr % 48) * 4;
        const size_t off = (size_t)b * 36864 + (size_t)i * LL + j4;

        float4 p = make_float4(0.f, 0.f, 0.f, 0.f);
#pragma unroll
        for (int s = 0; s < 8; ++s) {
            const float4 v = *(const float4*)(cpart + (size_t)s * 147456 + off);
            p.x += v.x; p.y += v.y; p.z += v.z; p.w += v.w;
        }
        const float4 hw = *(const float4*)(hfw_ws + b * LL + j4);
        const float hs = hfw_ws[768 + b * LL + i];
        const float bc = bc_ws[0];
        const float bg = b_gc[0];

        float4 o;
        o.x = 0.5f * (p.x + hw.x + hs + bc) + bg;
        o.y = 0.5f * (p.y + hw.y + hs + bc) + bg;
        o.z = 0.5f * (p.z + hw.z + hs + bc) + bg;
        o.w = 0.5f * (p.w + hw.w + hs + bc) + bg;
        *(float4*)(out + 4704 + off) = o;
    } else if (bid < 162) {
        // ---- tag finalize ----
        const int idx = (bid - 144) * 256 + tid;   // 0..4607
        const int r = idx / 6, c = idx % 6;
        const int b = r / LL;
        const float v = traw[r * 6 + c] + tb_ws[b * 8 + c];
        if (c < 3) out[96 + r * 3 + c] = v;
        else       out[2400 + r * 3 + (c - 3)] = v;
    } else {
        // ---- relh reduce + stage1 GEMV ----
        for (int i = tid; i < 4 * Hh; i += 256) {
            const int b = i / Hh, o = i % Hh;
            float s = b_relh[o];
#pragma unroll
            for (int kc = 0; kc < 8; ++kc)
                s += relh_part[(size_t)(kc * 4 + b) * Hh + o];
            pool[i] = fmaxf(s, 0.f);
        }
        __syncthreads();
        if (tid < 96) {
            const int b = tid / RR, rj = tid % RR;
            float s = b_rj[rj];
            for (int k = 0; k < Hh; ++k)
                s += pool[b * Hh + k] * W_rj[k * RR + rj];
            out[b * RR + rj] = s;
        }
    }
}

extern "C" void kernel_launch(void* const* d_in, const int* in_sizes, int n_in,
                              void* d_out, int out_size, void* d_ws, size_t ws_size,
                              hipStream_t stream) {
    const float* emb    = (const float*)d_in[0];
    const int*   mask   = (const int*)d_in[1];
    const int*   trel   = (const int*)d_in[2];
    const float* W_relh = (const float*)d_in[3];
    const float* b_relh = (const float*)d_in[4];
    const float* W_rj   = (const float*)d_in[5];
    const float* b_rj   = (const float*)d_in[6];
    const float* W_corr = (const float*)d_in[7];
    const float* b_corr = (const float*)d_in[8];
    const float* W_gc   = (const float*)d_in[9];
    const float* b_gc   = (const float*)d_in[10];
    const float* relemb = (const float*)d_in[11];
    const float* W_tag  = (const float*)d_in[12];
    const float* b_tag  = (const float*)d_in[13];
    const float* W_sub  = (const float*)d_in[14];
    const float* b_sub  = (const float*)d_in[15];
    const float* W_obj  = (const float*)d_in[16];
    const float* b_obj  = (const float*)d_in[17];

    float* out = (float*)d_out;
    float* ws  = (float*)d_ws;
    float* hfb  = ws;                              // HH
    float* hsb  = ws + (size_t)HH;                 // HH
    float* W8_ws     = ws + (size_t)2 * HH;        // 6144
    float* V8_ws     = W8_ws + 8 * H;              // 6144
    float* relh_part = V8_ws + 8 * H;              // 12288
    float* hfw_ws    = relh_part + 32 * Hh;        // 1536
    float* traw      = hfw_ws + 1536;              // 4608
    float* tb_ws     = traw + 4608;                // 32
    float* cb_ws     = tb_ws + 32;                 // 8
    float* bc_ws     = cb_ws + 8;                  // 8
    float* cpart     = bc_ws + 8 + 120;            // 8*147456

    k_A<<<673, 256, 0, stream>>>(emb, mask, W_corr, W_tag, W_gc, W_relh,
                                 W_sub, b_sub, W_obj, b_obj, b_tag, b_corr,
                                 hfb, hsb, relh_part, W8_ws, V8_ws, cb_ws, bc_ws);
    k_B<<<769, 256, 0, stream>>>(hfb, hsb, emb, W8_ws, V8_ws, cb_ws,
                                 trel, relemb, W_gc,
                                 cpart, hfw_ws, traw, tb_ws);
    k_C<<<163, 256, 0, stream>>>(cpart, hfw_ws, traw, tb_ws, bc_ws,
                                 relh_part, b_relh, W_rj, b_rj, b_gc, out);
}

// Round 14
// 47.337 us; speedup vs baseline: 1.0735x; 1.0735x over previous
//
#include <hip/hip_runtime.h>

#define H   768
#define Hh  384
#define LL  192
#define RR  24
#define HH  589824   // 768*768

typedef __attribute__((ext_vector_type(8))) short bf16x8;
typedef __attribute__((ext_vector_type(4))) float f32x4;

__device__ __forceinline__ unsigned short f2bf(float f) {
    unsigned int u = __float_as_uint(f);
    return (unsigned short)((u + 0x7FFF + ((u >> 16) & 1)) >> 16);  // RNE
}

__device__ __forceinline__ void gload16(const void* g, void* l) {
    __builtin_amdgcn_global_load_lds(
        (const __attribute__((address_space(1))) unsigned int*)g,
        (__attribute__((address_space(3))) unsigned int*)l, 16, 0, 0);
}

__device__ __forceinline__ float wred(float v) {
#pragma unroll
    for (int off = 1; off < 64; off <<= 1) v += __shfl_xor(v, off);
    return v;
}

// ---------------------------------------------------------------------------
// k_pre: grid 1105 x 256  (identical to R12)
//   [0,192)     : avg-pool PARTIALS -> part[lc][b][768], msum_part
//   [192,336)   : emb -> bf16                          -> embh
//   [336,912)   : W_corr halves -> bf16 transposed     -> wct0/wct1
//   [912,1104)  : W8/V8 build (wave per k)
//   1104        : cb + bc
// ---------------------------------------------------------------------------
__global__ __launch_bounds__(256) void k_pre(
    const float* __restrict__ emb, const int* __restrict__ mask,
    const float* __restrict__ W_corr, const float* __restrict__ W_tag,
    const float* __restrict__ W_gc, const float* __restrict__ b_corr,
    const float* __restrict__ W_sub, const float* __restrict__ b_sub,
    const float* __restrict__ W_obj, const float* __restrict__ b_obj,
    const float* __restrict__ b_tag,
    float* __restrict__ part, float* __restrict__ msum_part,
    unsigned short* __restrict__ embh,
    unsigned short* __restrict__ wct0, unsigned short* __restrict__ wct1,
    float* __restrict__ W8_ws, float* __restrict__ V8_ws,
    float* __restrict__ cb_ws, float* __restrict__ bc_ws)
{
    const int bid = blockIdx.x, tid = threadIdx.x;

    if (bid < 192) {
        // ---- avg-pool partial: b, h-chunk of 128, l-chunk of 24 ----
        __shared__ float4 red4[8][32];
        const int b   = bid / 48;
        const int rem = bid % 48;
        const int hc  = rem / 8;
        const int lc  = rem % 8;
        const int h0  = hc * 128;
        const int l0  = lc * 24;
        const int tx = tid & 31, ty = tid >> 5;

        float4 acc = make_float4(0.f, 0.f, 0.f, 0.f);
#pragma unroll
        for (int r = 0; r < 3; ++r) {
            const int l = l0 + r * 8 + ty;
            const float m = (float)mask[b * LL + l];
            const float4 v = *(const float4*)(emb + (size_t)(b * LL + l) * H + h0 + tx * 4);
            acc.x += v.x * m; acc.y += v.y * m; acc.z += v.z * m; acc.w += v.w * m;
        }
        red4[ty][tx] = acc;
        if (hc == 0 && tid == 0) {
            float s = 0.f;
            for (int l = l0; l < l0 + 24; ++l) s += (float)mask[b * LL + l];
            msum_part[b * 8 + lc] = s;
        }
        __syncthreads();
        if (tid < 32) {
            float4 s = red4[0][tid];
#pragma unroll
            for (int r = 1; r < 8; ++r) {
                s.x += red4[r][tid].x; s.y += red4[r][tid].y;
                s.z += red4[r][tid].z; s.w += red4[r][tid].w;
            }
            *(float4*)(part + (size_t)lc * 4 * H + (size_t)b * H + h0 + tid * 4) = s;
        }
        return;
    }

    if (bid < 336) {
        // ---- emb -> bf16 ----
        const size_t t = (size_t)(bid - 192) * 256 + tid;
        const float* s = emb + t * 16;
        union { unsigned short u[16]; uint4 v[2]; } pk;
#pragma unroll
        for (int q = 0; q < 4; ++q) {
            const float4 v = *(const float4*)(s + q * 4);
            pk.u[q * 4 + 0] = f2bf(v.x); pk.u[q * 4 + 1] = f2bf(v.y);
            pk.u[q * 4 + 2] = f2bf(v.z); pk.u[q * 4 + 3] = f2bf(v.w);
        }
        *(uint4*)(embh + t * 16)     = pk.v[0];
        *(uint4*)(embh + t * 16 + 8) = pk.v[1];
        return;
    }

    if (bid < 912) {
        // ---- W_corr halves -> bf16 transposed [n][k] ----
        const int local = bid - 336;          // 0..575
        const int m  = local / 288;
        const int r2 = local % 288;
        const int ko = r2 / 3, nb = r2 % 3;
        const int n  = nb * 256 + tid;
        const float* src = (m == 0) ? W_corr : W_corr + HH;
        unsigned short* dst = (m == 0) ? wct0 : wct1;
        union { unsigned short u[8]; uint4 v; } pk;
#pragma unroll
        for (int q = 0; q < 8; ++q)
            pk.u[q] = f2bf(src[(size_t)(ko * 8 + q) * H + n]);
        *(uint4*)(dst + (size_t)n * H + ko * 8) = pk.v;
        return;
    }

    if (bid < 1104) {
        // ---- W8/V8 build: wave per k ----
        const int wave = tid >> 6, lane = tid & 63;
        const int k = (bid - 912) * 4 + wave;
        const float* rc0 = W_corr + (size_t)k * H;
        const float* rc1 = W_corr + (size_t)HH + (size_t)k * H;
        const float* rtl = W_tag + (size_t)k * H;
        const float* rth = W_tag + (size_t)(H + k) * H;
        float u0 = 0.f, u1 = 0.f;
        float wsv[3] = {0, 0, 0}, wov[3] = {0, 0, 0};
        float vsv[3] = {0, 0, 0}, vov[3] = {0, 0, 0};
#pragma unroll
        for (int it = 0; it < 3; ++it) {
            const int h = lane * 4 + it * 256;
            const float4 c0 = *(const float4*)(rc0 + h);
            const float4 c1 = *(const float4*)(rc1 + h);
            const float4 tl = *(const float4*)(rtl + h);
            const float4 th = *(const float4*)(rth + h);
            const float4 g  = *(const float4*)(W_gc + h);
            float su[12], ob[12];
            *(float4*)&su[0] = *(const float4*)(W_sub + h * 3);
            *(float4*)&su[4] = *(const float4*)(W_sub + h * 3 + 4);
            *(float4*)&su[8] = *(const float4*)(W_sub + h * 3 + 8);
            *(float4*)&ob[0] = *(const float4*)(W_obj + h * 3);
            *(float4*)&ob[4] = *(const float4*)(W_obj + h * 3 + 4);
            *(float4*)&ob[8] = *(const float4*)(W_obj + h * 3 + 8);
            u0 += c0.x * g.x + c0.y * g.y + c0.z * g.z + c0.w * g.w;
            u1 += c1.x * g.x + c1.y * g.y + c1.z * g.z + c1.w * g.w;
            const float t4[4] = {th.x, th.y, th.z, th.w};
            const float l4[4] = {tl.x, tl.y, tl.z, tl.w};
#pragma unroll
            for (int d = 0; d < 4; ++d)
#pragma unroll
                for (int c = 0; c < 3; ++c) {
                    wsv[c] += t4[d] * su[d * 3 + c];
                    vsv[c] += l4[d] * su[d * 3 + c];
                    wov[c] += t4[d] * ob[d * 3 + c];
                    vov[c] += l4[d] * ob[d * 3 + c];
                }
        }
        u0 = wred(u0); u1 = wred(u1);
#pragma unroll
        for (int c = 0; c < 3; ++c) {
            wsv[c] = wred(wsv[c]); wov[c] = wred(wov[c]);
            vsv[c] = wred(vsv[c]); vov[c] = wred(vov[c]);
        }
        if (lane == 0) {
            *(float4*)(W8_ws + k * 8)     = make_float4(u0, u1, wsv[0], wsv[1]);
            *(float4*)(W8_ws + k * 8 + 4) = make_float4(wsv[2], wov[0], wov[1], wov[2]);
            *(float4*)(V8_ws + k * 8)     = make_float4(vsv[0], vsv[1], vsv[2], vov[0]);
            *(float4*)(V8_ws + k * 8 + 4) = make_float4(vov[1], vov[2], 0.f, 0.f);
        }
        return;
    }

    // ---- bid == 1104: cb + bc ----
    {
        const int wave = tid >> 6, lane = tid & 63;
        if (wave == 0) {
            float cs[3] = {0, 0, 0}, co[3] = {0, 0, 0};
#pragma unroll
            for (int it = 0; it < 3; ++it) {
                const int h = lane * 4 + it * 256;
                const float4 bt = *(const float4*)(b_tag + h);
                float su[12], ob[12];
                *(float4*)&su[0] = *(const float4*)(W_sub + h * 3);
                *(float4*)&su[4] = *(const float4*)(W_sub + h * 3 + 4);
                *(float4*)&su[8] = *(const float4*)(W_sub + h * 3 + 8);
                *(float4*)&ob[0] = *(const float4*)(W_obj + h * 3);
                *(float4*)&ob[4] = *(const float4*)(W_obj + h * 3 + 4);
                *(float4*)&ob[8] = *(const float4*)(W_obj + h * 3 + 8);
                const float b4[4] = {bt.x, bt.y, bt.z, bt.w};
#pragma unroll
                for (int d = 0; d < 4; ++d)
#pragma unroll
                    for (int c = 0; c < 3; ++c) {
                        cs[c] += b4[d] * su[d * 3 + c];
                        co[c] += b4[d] * ob[d * 3 + c];
                    }
            }
#pragma unroll
            for (int c = 0; c < 3; ++c) { cs[c] = wred(cs[c]); co[c] = wred(co[c]); }
            if (lane == 0) {
#pragma unroll
                for (int c = 0; c < 3; ++c) {
                    cb_ws[c]     = cs[c] + b_sub[c];
                    cb_ws[3 + c] = co[c] + b_obj[c];
                }
            }
        } else if (wave == 1) {
            float s = 0.f;
#pragma unroll
            for (int it = 0; it < 3; ++it) {
                const int h = lane * 4 + it * 256;
                const float4 bcv = *(const float4*)(b_corr + h);
                const float4 g   = *(const float4*)(W_gc + h);
                s += bcv.x * g.x + bcv.y * g.y + bcv.z * g.z + bcv.w * g.w;
            }
            s = wred(s);
            if (lane == 0) bc_ws[0] = s;
        }
    }
}

// ---------------------------------------------------------------------------
// k_main: grid 674 x 256
//   [0,288)   : bf16 MFMA GEMM 64x64, BK=64 (R12's gload_lds staging)
//   [288,480) : relh partials (k-split x8); avg folded from part[]
//   [480,673) : row-dots: hfw/hsw -> hfw_ws; raw tag dots -> traw
//   673       : tb[b][0..5] = rel_e . V8 + cb  -> tb_ws
// ---------------------------------------------------------------------------
__global__ __launch_bounds__(256) void k_main(
    const unsigned short* __restrict__ embh, const unsigned short* __restrict__ wct0,
    const unsigned short* __restrict__ wct1, const float* __restrict__ b_corr,
    const float* __restrict__ W_relh, const float* __restrict__ part,
    const float* __restrict__ msum_part,
    const int* __restrict__ target_rel, const float* __restrict__ rel_emb,
    const float* __restrict__ V8_ws, const float* __restrict__ cb_ws,
    const float* __restrict__ emb, const float* __restrict__ W8_ws,
    float* __restrict__ hfb, float* __restrict__ hsb,
    float* __restrict__ relh_part, float* __restrict__ hfw_ws,
    float* __restrict__ traw, float* __restrict__ tb_ws)
{
    __shared__ unsigned short As[2][4096];
    __shared__ unsigned short Bs[2][4096];
    const int bid = blockIdx.x, tid = threadIdx.x;

    if (bid >= 288) {
        if (bid < 480) {
            // ---- relh partials, avg reconstructed from l-split partials ----
            float* red  = (float*)&As[0][0];   // 256 floats
            float* avgS = red + 256;           // 96 floats
            const int rb = bid - 288;
            const int kc = rb & 7;
            const int t2 = rb >> 3;
            const int b  = t2 / 6;
            const int o0 = (t2 % 6) * 64;
            const int tx = tid & 63, ty = tid >> 6;
            if (tid < 96) {
                const int h = kc * 96 + tid;
                float s = 0.f;
#pragma unroll
                for (int lc = 0; lc < 8; ++lc)
                    s += part[(size_t)lc * 4 * H + (size_t)b * H + h];
                float ms = 0.f;
#pragma unroll
                for (int lc = 0; lc < 8; ++lc) ms += msum_part[b * 8 + lc];
                avgS[tid] = s / ms;
            }
            __syncthreads();
            const int hl0 = ty * 24;
            float s = 0.f;
            for (int hh = 0; hh < 24; ++hh)
                s += avgS[hl0 + hh] *
                     W_relh[(size_t)(kc * 96 + hl0 + hh) * Hh + o0 + tx];
            red[ty * 64 + tx] = s;
            __syncthreads();
            if (ty == 0)
                relh_part[(size_t)(kc * 4 + b) * Hh + o0 + tx] =
                    red[tx] + red[64 + tx] + red[128 + tx] + red[192 + tx];
        } else if (bid < 673) {
            // ---- row-dots: wave per emb row ----
            const int wave = tid >> 6, lane = tid & 63;
            const int r = (bid - 480) * 4 + wave;   // 0..771
            if (r < 768) {
                const float* er = emb + (size_t)r * H;
                float s0 = 0.f, s1 = 0.f;
                float t[6] = {0, 0, 0, 0, 0, 0};
#pragma unroll
                for (int it = 0; it < 12; ++it) {
                    const int h = lane + it * 64;
                    const float e = er[h];
                    const float4 a = *(const float4*)(W8_ws + h * 8);
                    const float4 v = *(const float4*)(W8_ws + h * 8 + 4);
                    s0 += e * a.x; s1 += e * a.y;
                    t[0] += e * a.z; t[1] += e * a.w; t[2] += e * v.x;
                    t[3] += e * v.y; t[4] += e * v.z; t[5] += e * v.w;
                }
                s0 = wred(s0); s1 = wred(s1);
#pragma unroll
                for (int c = 0; c < 6; ++c) t[c] = wred(t[c]);
                if (lane == 0) {
                    hfw_ws[r] = s0;
                    hfw_ws[768 + r] = s1;
#pragma unroll
                    for (int c = 0; c < 6; ++c) traw[r * 6 + c] = t[c];
                }
            }
        } else {
            // ---- tb: wave per batch ----
            const int b = tid >> 6, lane = tid & 63;
            const float* re = rel_emb + (size_t)target_rel[b] * H;
            float t[6] = {0, 0, 0, 0, 0, 0};
#pragma unroll
            for (int it = 0; it < 12; ++it) {
                const int k = lane + it * 64;
                const float rl = re[k];
                const float4 a = *(const float4*)(V8_ws + k * 8);
                const float4 v = *(const float4*)(V8_ws + k * 8 + 4);
                t[0] += rl * a.x; t[1] += rl * a.y; t[2] += rl * a.z;
                t[3] += rl * a.w; t[4] += rl * v.x; t[5] += rl * v.y;
            }
#pragma unroll
            for (int c = 0; c < 6; ++c) t[c] = wred(t[c]);
            if (lane == 0) {
#pragma unroll
                for (int c = 0; c < 6; ++c)
                    tb_ws[b * 8 + c] = t[c] + cb_ws[c];
            }
        }
        return;
    }

    // ------------------ MFMA GEMM (R12's gload_lds staging) ------------------
    const int sel = bid / 144;
    const int tt  = bid % 144;
    const int mt = tt % 12, nt = tt / 12;
    const int m0 = mt * 64, n0 = nt * 64;
    const unsigned short* Bsrc = sel ? wct1 : wct0;
    float* C = sel ? hsb : hfb;

    const int wv = tid >> 6, ln = tid & 63;
    const int lr = ln & 15, ko = ln >> 4;
    const int wr = (wv >> 1) * 32, wc = (wv & 1) * 32;

    f32x4 acc[2][2];
#pragma unroll
    for (int mi = 0; mi < 2; ++mi)
#pragma unroll
        for (int ni = 0; ni < 2; ++ni)
            acc[mi][ni] = (f32x4){0.f, 0.f, 0.f, 0.f};

    auto stage = [&](int buf, int k0) {
#pragma unroll
        for (int it = 0; it < 2; ++it) {
            const int sbase = it * 256 + wv * 64;
            const int slot = sbase + ln;
            const int r = slot >> 3, c = slot & 7;
            const int cs = c ^ (r & 7);
            gload16(embh + (size_t)(m0 + r) * H + k0 + cs * 8, &As[buf][sbase * 8]);
            gload16(Bsrc + (size_t)(n0 + r) * H + k0 + cs * 8, &Bs[buf][sbase * 8]);
        }
    };

    stage(0, 0);
    int cur = 0;
    for (int ks = 0; ks < 12; ++ks) {
        __syncthreads();
        if (ks < 11) stage(cur ^ 1, (ks + 1) * 64);
        bf16x8 af[2][2], bfr[2][2];
#pragma unroll
        for (int mi = 0; mi < 2; ++mi) {
            const int r = wr + mi * 16 + lr;
#pragma unroll
            for (int kc = 0; kc < 2; ++kc) {
                const int qs = (kc * 4 + ko) ^ (r & 7);
                af[kc][mi] = *(const bf16x8*)(&As[cur][r * 64 + qs * 8]);
            }
        }
#pragma unroll
        for (int ni = 0; ni < 2; ++ni) {
            const int r = wc + ni * 16 + lr;
#pragma unroll
            for (int kc = 0; kc < 2; ++kc) {
                const int qs = (kc * 4 + ko) ^ (r & 7);
                bfr[kc][ni] = *(const bf16x8*)(&Bs[cur][r * 64 + qs * 8]);
            }
        }
#pragma unroll
        for (int kc = 0; kc < 2; ++kc)
#pragma unroll
            for (int mi = 0; mi < 2; ++mi)
#pragma unroll
                for (int ni = 0; ni < 2; ++ni)
                    acc[mi][ni] = __builtin_amdgcn_mfma_f32_16x16x32_bf16(
                        af[kc][mi], bfr[kc][ni], acc[mi][ni], 0, 0, 0);
        cur ^= 1;
    }

    float cbv[2];
#pragma unroll
    for (int ni = 0; ni < 2; ++ni)
        cbv[ni] = (sel == 0) ? b_corr[n0 + wc + ni * 16 + lr] : 0.f;
#pragma unroll
    for (int mi = 0; mi < 2; ++mi)
#pragma unroll
        for (int ni = 0; ni < 2; ++ni) {
            const int m = m0 + wr + mi * 16 + ko * 4;
            const int n = n0 + wc + ni * 16 + lr;
#pragma unroll
            for (int rr = 0; rr < 4; ++rr)
                C[(size_t)(m + rr) * H + n] = acc[mi][ni][rr] + cbv[ni];
        }
}

// ---------------------------------------------------------------------------
// k_tail: grid 577 x 256
//   [0,576)  : corres abs-partials, 64i x 32j, h-split 8 (R12 structure)
//   576      : relh reduce + stage1 GEMV
// ---------------------------------------------------------------------------
__global__ __launch_bounds__(256) void k_tail(
    const float* __restrict__ hfb, const float* __restrict__ hsb,
    const float* __restrict__ relh_part, const float* __restrict__ b_relh,
    const float* __restrict__ W_gc, const float* __restrict__ W_rj,
    const float* __restrict__ b_rj,
    float* __restrict__ cpart, float* __restrict__ out)
{
    __shared__ float hfT[96][34];   // 13 KB
    const int bid = blockIdx.x, tid = threadIdx.x;

    if (bid < 576) {
        const int s    = bid & 7;
        const int tile = bid >> 3;
        const int b   = tile / 18;
        const int rem = tile % 18;
        const int i0  = (rem / 6) * 64;
        const int j0  = (rem % 6) * 32;
        const int h0  = s * 96;
        const int tx = tid & 15, ty = tid >> 4;

#pragma unroll
        for (int it = 0; it < 3; ++it) {
            const int j = tid >> 3, q = tid & 7;
            const int k = it * 32 + q * 4;
            const float4 fv = *(const float4*)(hfb + (size_t)(b * LL + j0 + j) * H + h0 + k);
            hfT[k + 0][j] = fv.x;
            hfT[k + 1][j] = fv.y;
            hfT[k + 2][j] = fv.z;
            hfT[k + 3][j] = fv.w;
        }
        __syncthreads();

        float acc[4][2] = {{0.f}};
        float hsr[4][8];
        const float* hsbase = hsb + (size_t)(b * LL + i0 + ty * 4) * H + h0;

        for (int kb = 0; kb < 96; kb += 8) {
#pragma unroll
            for (int ii = 0; ii < 4; ++ii) {
                const float4 v0 = *(const float4*)(hsbase + (size_t)ii * H + kb);
                const float4 v1 = *(const float4*)(hsbase + (size_t)ii * H + kb + 4);
                hsr[ii][0] = v0.x; hsr[ii][1] = v0.y; hsr[ii][2] = v0.z; hsr[ii][3] = v0.w;
                hsr[ii][4] = v1.x; hsr[ii][5] = v1.y; hsr[ii][6] = v1.z; hsr[ii][7] = v1.w;
            }
            const float4 wa = *(const float4*)(W_gc + h0 + kb);
            const float4 wb = *(const float4*)(W_gc + h0 + kb + 4);
            const float wreg[8] = {wa.x, wa.y, wa.z, wa.w, wb.x, wb.y, wb.z, wb.w};
#pragma unroll
            for (int k8 = 0; k8 < 8; ++k8) {
                const int kk = kb + k8;
                const float2 f2 = *(const float2*)&hfT[kk][tx * 2];
                const float w = wreg[k8];
#pragma unroll
                for (int ii = 0; ii < 4; ++ii) {
                    acc[ii][0] += fabsf(f2.x + hsr[ii][k8]) * w;
                    acc[ii][1] += fabsf(f2.y + hsr[ii][k8]) * w;
                }
            }
        }
#pragma unroll
        for (int ii = 0; ii < 4; ++ii) {
            *(float2*)(cpart + (size_t)s * 147456 + (size_t)b * 36864
                       + (size_t)(i0 + ty * 4 + ii) * LL + j0 + tx * 2) =
                make_float2(acc[ii][0], acc[ii][1]);
        }
    } else {
        // ---- relh reduce + stage1 GEMV ----
        float* relhS = &hfT[0][0];   // 1536 floats
        for (int i = tid; i < 4 * Hh; i += 256) {
            const int b = i / Hh, o = i % Hh;
            float s = b_relh[o];
#pragma unroll
            for (int kc = 0; kc < 8; ++kc)
                s += relh_part[(size_t)(kc * 4 + b) * Hh + o];
            relhS[i] = fmaxf(s, 0.f);
        }
        __syncthreads();
        if (tid < 96) {
            const int b = tid / RR, rj = tid % RR;
            float s = b_rj[rj];
            for (int k = 0; k < Hh; ++k)
                s += relhS[b * Hh + k] * W_rj[k * RR + rj];
            out[b * RR + rj] = s;
        }
    }
}

// ---------------------------------------------------------------------------
// k_merge: grid 162 x 256
//   [0,144)  : corres merge
//   [144,162): tag finalize: out = traw + tb
// ---------------------------------------------------------------------------
__global__ __launch_bounds__(256) void k_merge(
    const float* __restrict__ cpart, const float* __restrict__ hfw_ws,
    const float* __restrict__ traw, const float* __restrict__ tb_ws,
    const float* __restrict__ bc_ws, const float* __restrict__ b_gc,
    float* __restrict__ out)
{
    const int bid = blockIdx.x, tid = threadIdx.x;

    if (bid < 144) {
        const int idx = bid * 256 + tid;
        const int b  = idx / 9216;
        const int rr = idx % 9216;
        const int i  = rr / 48;
        const int j4 = (rr % 48) * 4;
        const size_t off = (size_t)b * 36864 + (size_t)i * LL + j4;

        float4 p = make_float4(0.f, 0.f, 0.f, 0.f);
#pragma unroll
        for (int s = 0; s < 8; ++s) {
            const float4 v = *(const float4*)(cpart + (size_t)s * 147456 + off);
            p.x += v.x; p.y += v.y; p.z += v.z; p.w += v.w;
        }
        const float4 hw = *(const float4*)(hfw_ws + b * LL + j4);
        const float hs = hfw_ws[768 + b * LL + i];
        const float bc = bc_ws[0];
        const float bg = b_gc[0];

        float4 o;
        o.x = 0.5f * (p.x + hw.x + hs + bc) + bg;
        o.y = 0.5f * (p.y + hw.y + hs + bc) + bg;
        o.z = 0.5f * (p.z + hw.z + hs + bc) + bg;
        o.w = 0.5f * (p.w + hw.w + hs + bc) + bg;
        *(float4*)(out + 4704 + off) = o;
    } else {
        // ---- tag finalize ----
        const int idx = (bid - 144) * 256 + tid;   // 0..4607
        if (idx < 4608) {
            const int r = idx / 6, c = idx % 6;
            const int b = r / LL;
            const float v = traw[r * 6 + c] + tb_ws[b * 8 + c];
            if (c < 3) out[96 + r * 3 + c] = v;
            else       out[2400 + r * 3 + (c - 3)] = v;
        }
    }
}

extern "C" void kernel_launch(void* const* d_in, const int* in_sizes, int n_in,
                              void* d_out, int out_size, void* d_ws, size_t ws_size,
                              hipStream_t stream) {
    const float* emb    = (const float*)d_in[0];
    const int*   mask   = (const int*)d_in[1];
    const int*   trel   = (const int*)d_in[2];
    const float* W_relh = (const float*)d_in[3];
    const float* b_relh = (const float*)d_in[4];
    const float* W_rj   = (const float*)d_in[5];
    const float* b_rj   = (const float*)d_in[6];
    const float* W_corr = (const float*)d_in[7];
    const float* b_corr = (const float*)d_in[8];
    const float* W_gc   = (const float*)d_in[9];
    const float* b_gc   = (const float*)d_in[10];
    const float* relemb = (const float*)d_in[11];
    const float* W_tag  = (const float*)d_in[12];
    const float* b_tag  = (const float*)d_in[13];
    const float* W_sub  = (const float*)d_in[14];
    const float* b_sub  = (const float*)d_in[15];
    const float* W_obj  = (const float*)d_in[16];
    const float* b_obj  = (const float*)d_in[17];

    float* out = (float*)d_out;
    float* ws  = (float*)d_ws;
    float* hfb  = ws;                              // HH
    float* hsb  = ws + (size_t)HH;                 // HH
    unsigned short* embh = (unsigned short*)(ws + (size_t)2 * HH);
    unsigned short* wct0 = embh + (size_t)HH;
    unsigned short* wct1 = wct0 + (size_t)HH;
    float* smalls    = ws + (size_t)2 * HH + (size_t)3 * HH / 2;
    float* part      = smalls;                     // 24576
    float* msum_part = part + 24576;               // 32
    float* W8_ws     = msum_part + 32;             // 6144
    float* V8_ws     = W8_ws + 8 * H;              // 6144
    float* relh_part = V8_ws + 8 * H;              // 12288
    float* hfw_ws    = relh_part + 32 * Hh;        // 1536
    float* traw      = hfw_ws + 1536;              // 4608
    float* tb_ws     = traw + 4608;                // 32
    float* cb_ws     = tb_ws + 32;                 // 8
    float* bc_ws     = cb_ws + 8;                  // 8
    float* cpart     = bc_ws + 8 + 120;            // 8*147456

    k_pre<<<1105, 256, 0, stream>>>(emb, mask, W_corr, W_tag, W_gc, b_corr,
                                    W_sub, b_sub, W_obj, b_obj, b_tag,
                                    part, msum_part, embh, wct0, wct1,
                                    W8_ws, V8_ws, cb_ws, bc_ws);
    k_main<<<674, 256, 0, stream>>>(embh, wct0, wct1, b_corr,
                                    W_relh, part, msum_part, trel, relemb,
                                    V8_ws, cb_ws, emb, W8_ws,
                                    hfb, hsb, relh_part, hfw_ws, traw, tb_ws);
    k_tail<<<577, 256, 0, stream>>>(hfb, hsb, relh_part, b_relh,
                                    W_gc, W_rj, b_rj, cpart, out);
    k_merge<<<162, 256, 0, stream>>>(cpart, hfw_ws, traw, tb_ws,
                                     bc_ws, b_gc, out);
}

// Round 15
// 46.772 us; speedup vs baseline: 1.0865x; 1.0121x over previous
//
#include <hip/hip_runtime.h>

#define H   768
#define Hh  384
#define LL  192
#define RR  24
#define HH  589824   // 768*768

typedef __attribute__((ext_vector_type(8))) short bf16x8;
typedef __attribute__((ext_vector_type(4))) float f32x4;

__device__ __forceinline__ unsigned short f2bf(float f) {
    unsigned int u = __float_as_uint(f);
    return (unsigned short)((u + 0x7FFF + ((u >> 16) & 1)) >> 16);  // RNE
}

__device__ __forceinline__ float bf2f(unsigned short u) {
    return __uint_as_float((unsigned int)u << 16);
}

__device__ __forceinline__ void gload16(const void* g, void* l) {
    __builtin_amdgcn_global_load_lds(
        (const __attribute__((address_space(1))) unsigned int*)g,
        (__attribute__((address_space(3))) unsigned int*)l, 16, 0, 0);
}

__device__ __forceinline__ float wred(float v) {
#pragma unroll
    for (int off = 1; off < 64; off <<= 1) v += __shfl_xor(v, off);
    return v;
}

// ---------------------------------------------------------------------------
// k_pre: grid 1105 x 256  (identical to R14)
// ---------------------------------------------------------------------------
__global__ __launch_bounds__(256) void k_pre(
    const float* __restrict__ emb, const int* __restrict__ mask,
    const float* __restrict__ W_corr, const float* __restrict__ W_tag,
    const float* __restrict__ W_gc, const float* __restrict__ b_corr,
    const float* __restrict__ W_sub, const float* __restrict__ b_sub,
    const float* __restrict__ W_obj, const float* __restrict__ b_obj,
    const float* __restrict__ b_tag,
    float* __restrict__ part, float* __restrict__ msum_part,
    unsigned short* __restrict__ embh,
    unsigned short* __restrict__ wct0, unsigned short* __restrict__ wct1,
    float* __restrict__ W8_ws, float* __restrict__ V8_ws,
    float* __restrict__ cb_ws, float* __restrict__ bc_ws)
{
    const int bid = blockIdx.x, tid = threadIdx.x;

    if (bid < 192) {
        // ---- avg-pool partial: b, h-chunk of 128, l-chunk of 24 ----
        __shared__ float4 red4[8][32];
        const int b   = bid / 48;
        const int rem = bid % 48;
        const int hc  = rem / 8;
        const int lc  = rem % 8;
        const int h0  = hc * 128;
        const int l0  = lc * 24;
        const int tx = tid & 31, ty = tid >> 5;

        float4 acc = make_float4(0.f, 0.f, 0.f, 0.f);
#pragma unroll
        for (int r = 0; r < 3; ++r) {
            const int l = l0 + r * 8 + ty;
            const float m = (float)mask[b * LL + l];
            const float4 v = *(const float4*)(emb + (size_t)(b * LL + l) * H + h0 + tx * 4);
            acc.x += v.x * m; acc.y += v.y * m; acc.z += v.z * m; acc.w += v.w * m;
        }
        red4[ty][tx] = acc;
        if (hc == 0 && tid == 0) {
            float s = 0.f;
            for (int l = l0; l < l0 + 24; ++l) s += (float)mask[b * LL + l];
            msum_part[b * 8 + lc] = s;
        }
        __syncthreads();
        if (tid < 32) {
            float4 s = red4[0][tid];
#pragma unroll
            for (int r = 1; r < 8; ++r) {
                s.x += red4[r][tid].x; s.y += red4[r][tid].y;
                s.z += red4[r][tid].z; s.w += red4[r][tid].w;
            }
            *(float4*)(part + (size_t)lc * 4 * H + (size_t)b * H + h0 + tid * 4) = s;
        }
        return;
    }

    if (bid < 336) {
        // ---- emb -> bf16 ----
        const size_t t = (size_t)(bid - 192) * 256 + tid;
        const float* s = emb + t * 16;
        union { unsigned short u[16]; uint4 v[2]; } pk;
#pragma unroll
        for (int q = 0; q < 4; ++q) {
            const float4 v = *(const float4*)(s + q * 4);
            pk.u[q * 4 + 0] = f2bf(v.x); pk.u[q * 4 + 1] = f2bf(v.y);
            pk.u[q * 4 + 2] = f2bf(v.z); pk.u[q * 4 + 3] = f2bf(v.w);
        }
        *(uint4*)(embh + t * 16)     = pk.v[0];
        *(uint4*)(embh + t * 16 + 8) = pk.v[1];
        return;
    }

    if (bid < 912) {
        // ---- W_corr halves -> bf16 transposed [n][k] ----
        const int local = bid - 336;          // 0..575
        const int m  = local / 288;
        const int r2 = local % 288;
        const int ko = r2 / 3, nb = r2 % 3;
        const int n  = nb * 256 + tid;
        const float* src = (m == 0) ? W_corr : W_corr + HH;
        unsigned short* dst = (m == 0) ? wct0 : wct1;
        union { unsigned short u[8]; uint4 v; } pk;
#pragma unroll
        for (int q = 0; q < 8; ++q)
            pk.u[q] = f2bf(src[(size_t)(ko * 8 + q) * H + n]);
        *(uint4*)(dst + (size_t)n * H + ko * 8) = pk.v;
        return;
    }

    if (bid < 1104) {
        // ---- W8/V8 build: wave per k ----
        const int wave = tid >> 6, lane = tid & 63;
        const int k = (bid - 912) * 4 + wave;
        const float* rc0 = W_corr + (size_t)k * H;
        const float* rc1 = W_corr + (size_t)HH + (size_t)k * H;
        const float* rtl = W_tag + (size_t)k * H;
        const float* rth = W_tag + (size_t)(H + k) * H;
        float u0 = 0.f, u1 = 0.f;
        float wsv[3] = {0, 0, 0}, wov[3] = {0, 0, 0};
        float vsv[3] = {0, 0, 0}, vov[3] = {0, 0, 0};
#pragma unroll
        for (int it = 0; it < 3; ++it) {
            const int h = lane * 4 + it * 256;
            const float4 c0 = *(const float4*)(rc0 + h);
            const float4 c1 = *(const float4*)(rc1 + h);
            const float4 tl = *(const float4*)(rtl + h);
            const float4 th = *(const float4*)(rth + h);
            const float4 g  = *(const float4*)(W_gc + h);
            float su[12], ob[12];
            *(float4*)&su[0] = *(const float4*)(W_sub + h * 3);
            *(float4*)&su[4] = *(const float4*)(W_sub + h * 3 + 4);
            *(float4*)&su[8] = *(const float4*)(W_sub + h * 3 + 8);
            *(float4*)&ob[0] = *(const float4*)(W_obj + h * 3);
            *(float4*)&ob[4] = *(const float4*)(W_obj + h * 3 + 4);
            *(float4*)&ob[8] = *(const float4*)(W_obj + h * 3 + 8);
            u0 += c0.x * g.x + c0.y * g.y + c0.z * g.z + c0.w * g.w;
            u1 += c1.x * g.x + c1.y * g.y + c1.z * g.z + c1.w * g.w;
            const float t4[4] = {th.x, th.y, th.z, th.w};
            const float l4[4] = {tl.x, tl.y, tl.z, tl.w};
#pragma unroll
            for (int d = 0; d < 4; ++d)
#pragma unroll
                for (int c = 0; c < 3; ++c) {
                    wsv[c] += t4[d] * su[d * 3 + c];
                    vsv[c] += l4[d] * su[d * 3 + c];
                    wov[c] += t4[d] * ob[d * 3 + c];
                    vov[c] += l4[d] * ob[d * 3 + c];
                }
        }
        u0 = wred(u0); u1 = wred(u1);
#pragma unroll
        for (int c = 0; c < 3; ++c) {
            wsv[c] = wred(wsv[c]); wov[c] = wred(wov[c]);
            vsv[c] = wred(vsv[c]); vov[c] = wred(vov[c]);
        }
        if (lane == 0) {
            *(float4*)(W8_ws + k * 8)     = make_float4(u0, u1, wsv[0], wsv[1]);
            *(float4*)(W8_ws + k * 8 + 4) = make_float4(wsv[2], wov[0], wov[1], wov[2]);
            *(float4*)(V8_ws + k * 8)     = make_float4(vsv[0], vsv[1], vsv[2], vov[0]);
            *(float4*)(V8_ws + k * 8 + 4) = make_float4(vov[1], vov[2], 0.f, 0.f);
        }
        return;
    }

    // ---- bid == 1104: cb + bc ----
    {
        const int wave = tid >> 6, lane = tid & 63;
        if (wave == 0) {
            float cs[3] = {0, 0, 0}, co[3] = {0, 0, 0};
#pragma unroll
            for (int it = 0; it < 3; ++it) {
                const int h = lane * 4 + it * 256;
                const float4 bt = *(const float4*)(b_tag + h);
                float su[12], ob[12];
                *(float4*)&su[0] = *(const float4*)(W_sub + h * 3);
                *(float4*)&su[4] = *(const float4*)(W_sub + h * 3 + 4);
                *(float4*)&su[8] = *(const float4*)(W_sub + h * 3 + 8);
                *(float4*)&ob[0] = *(const float4*)(W_obj + h * 3);
                *(float4*)&ob[4] = *(const float4*)(W_obj + h * 3 + 4);
                *(float4*)&ob[8] = *(const float4*)(W_obj + h * 3 + 8);
                const float b4[4] = {bt.x, bt.y, bt.z, bt.w};
#pragma unroll
                for (int d = 0; d < 4; ++d)
#pragma unroll
                    for (int c = 0; c < 3; ++c) {
                        cs[c] += b4[d] * su[d * 3 + c];
                        co[c] += b4[d] * ob[d * 3 + c];
                    }
            }
#pragma unroll
            for (int c = 0; c < 3; ++c) { cs[c] = wred(cs[c]); co[c] = wred(co[c]); }
            if (lane == 0) {
#pragma unroll
                for (int c = 0; c < 3; ++c) {
                    cb_ws[c]     = cs[c] + b_sub[c];
                    cb_ws[3 + c] = co[c] + b_obj[c];
                }
            }
        } else if (wave == 1) {
            float s = 0.f;
#pragma unroll
            for (int it = 0; it < 3; ++it) {
                const int h = lane * 4 + it * 256;
                const float4 bcv = *(const float4*)(b_corr + h);
                const float4 g   = *(const float4*)(W_gc + h);
                s += bcv.x * g.x + bcv.y * g.y + bcv.z * g.z + bcv.w * g.w;
            }
            s = wred(s);
            if (lane == 0) bc_ws[0] = s;
        }
    }
}

// ---------------------------------------------------------------------------
// k_main: grid 674 x 256  (R14 structure; GEMM C stored as BF16)
// ---------------------------------------------------------------------------
__global__ __launch_bounds__(256) void k_main(
    const unsigned short* __restrict__ embh, const unsigned short* __restrict__ wct0,
    const unsigned short* __restrict__ wct1, const float* __restrict__ b_corr,
    const float* __restrict__ W_relh, const float* __restrict__ part,
    const float* __restrict__ msum_part,
    const int* __restrict__ target_rel, const float* __restrict__ rel_emb,
    const float* __restrict__ V8_ws, const float* __restrict__ cb_ws,
    const float* __restrict__ emb, const float* __restrict__ W8_ws,
    unsigned short* __restrict__ hfbh, unsigned short* __restrict__ hsbh,
    float* __restrict__ relh_part, float* __restrict__ hfw_ws,
    float* __restrict__ traw, float* __restrict__ tb_ws)
{
    __shared__ unsigned short As[2][4096];
    __shared__ unsigned short Bs[2][4096];
    const int bid = blockIdx.x, tid = threadIdx.x;

    if (bid >= 288) {
        if (bid < 480) {
            // ---- relh partials, avg reconstructed from l-split partials ----
            float* red  = (float*)&As[0][0];   // 256 floats
            float* avgS = red + 256;           // 96 floats
            const int rb = bid - 288;
            const int kc = rb & 7;
            const int t2 = rb >> 3;
            const int b  = t2 / 6;
            const int o0 = (t2 % 6) * 64;
            const int tx = tid & 63, ty = tid >> 6;
            if (tid < 96) {
                const int h = kc * 96 + tid;
                float s = 0.f;
#pragma unroll
                for (int lc = 0; lc < 8; ++lc)
                    s += part[(size_t)lc * 4 * H + (size_t)b * H + h];
                float ms = 0.f;
#pragma unroll
                for (int lc = 0; lc < 8; ++lc) ms += msum_part[b * 8 + lc];
                avgS[tid] = s / ms;
            }
            __syncthreads();
            const int hl0 = ty * 24;
            float s = 0.f;
            for (int hh = 0; hh < 24; ++hh)
                s += avgS[hl0 + hh] *
                     W_relh[(size_t)(kc * 96 + hl0 + hh) * Hh + o0 + tx];
            red[ty * 64 + tx] = s;
            __syncthreads();
            if (ty == 0)
                relh_part[(size_t)(kc * 4 + b) * Hh + o0 + tx] =
                    red[tx] + red[64 + tx] + red[128 + tx] + red[192 + tx];
        } else if (bid < 673) {
            // ---- row-dots: wave per emb row ----
            const int wave = tid >> 6, lane = tid & 63;
            const int r = (bid - 480) * 4 + wave;   // 0..771
            if (r < 768) {
                const float* er = emb + (size_t)r * H;
                float s0 = 0.f, s1 = 0.f;
                float t[6] = {0, 0, 0, 0, 0, 0};
#pragma unroll
                for (int it = 0; it < 12; ++it) {
                    const int h = lane + it * 64;
                    const float e = er[h];
                    const float4 a = *(const float4*)(W8_ws + h * 8);
                    const float4 v = *(const float4*)(W8_ws + h * 8 + 4);
                    s0 += e * a.x; s1 += e * a.y;
                    t[0] += e * a.z; t[1] += e * a.w; t[2] += e * v.x;
                    t[3] += e * v.y; t[4] += e * v.z; t[5] += e * v.w;
                }
                s0 = wred(s0); s1 = wred(s1);
#pragma unroll
                for (int c = 0; c < 6; ++c) t[c] = wred(t[c]);
                if (lane == 0) {
                    hfw_ws[r] = s0;
                    hfw_ws[768 + r] = s1;
#pragma unroll
                    for (int c = 0; c < 6; ++c) traw[r * 6 + c] = t[c];
                }
            }
        } else {
            // ---- tb: wave per batch ----
            const int b = tid >> 6, lane = tid & 63;
            const float* re = rel_emb + (size_t)target_rel[b] * H;
            float t[6] = {0, 0, 0, 0, 0, 0};
#pragma unroll
            for (int it = 0; it < 12; ++it) {
                const int k = lane + it * 64;
                const float rl = re[k];
                const float4 a = *(const float4*)(V8_ws + k * 8);
                const float4 v = *(const float4*)(V8_ws + k * 8 + 4);
                t[0] += rl * a.x; t[1] += rl * a.y; t[2] += rl * a.z;
                t[3] += rl * a.w; t[4] += rl * v.x; t[5] += rl * v.y;
            }
#pragma unroll
            for (int c = 0; c < 6; ++c) t[c] = wred(t[c]);
            if (lane == 0) {
#pragma unroll
                for (int c = 0; c < 6; ++c)
                    tb_ws[b * 8 + c] = t[c] + cb_ws[c];
            }
        }
        return;
    }

    // ------------------ MFMA GEMM (gload_lds staging, bf16 C) ------------------
    const int sel = bid / 144;
    const int tt  = bid % 144;
    const int mt = tt % 12, nt = tt / 12;
    const int m0 = mt * 64, n0 = nt * 64;
    const unsigned short* Bsrc = sel ? wct1 : wct0;
    unsigned short* C = sel ? hsbh : hfbh;

    const int wv = tid >> 6, ln = tid & 63;
    const int lr = ln & 15, ko = ln >> 4;
    const int wr = (wv >> 1) * 32, wc = (wv & 1) * 32;

    f32x4 acc[2][2];
#pragma unroll
    for (int mi = 0; mi < 2; ++mi)
#pragma unroll
        for (int ni = 0; ni < 2; ++ni)
            acc[mi][ni] = (f32x4){0.f, 0.f, 0.f, 0.f};

    auto stage = [&](int buf, int k0) {
#pragma unroll
        for (int it = 0; it < 2; ++it) {
            const int sbase = it * 256 + wv * 64;
            const int slot = sbase + ln;
            const int r = slot >> 3, c = slot & 7;
            const int cs = c ^ (r & 7);
            gload16(embh + (size_t)(m0 + r) * H + k0 + cs * 8, &As[buf][sbase * 8]);
            gload16(Bsrc + (size_t)(n0 + r) * H + k0 + cs * 8, &Bs[buf][sbase * 8]);
        }
    };

    stage(0, 0);
    int cur = 0;
    for (int ks = 0; ks < 12; ++ks) {
        __syncthreads();
        if (ks < 11) stage(cur ^ 1, (ks + 1) * 64);
        bf16x8 af[2][2], bfr[2][2];
#pragma unroll
        for (int mi = 0; mi < 2; ++mi) {
            const int r = wr + mi * 16 + lr;
#pragma unroll
            for (int kc = 0; kc < 2; ++kc) {
                const int qs = (kc * 4 + ko) ^ (r & 7);
                af[kc][mi] = *(const bf16x8*)(&As[cur][r * 64 + qs * 8]);
            }
        }
#pragma unroll
        for (int ni = 0; ni < 2; ++ni) {
            const int r = wc + ni * 16 + lr;
#pragma unroll
            for (int kc = 0; kc < 2; ++kc) {
                const int qs = (kc * 4 + ko) ^ (r & 7);
                bfr[kc][ni] = *(const bf16x8*)(&Bs[cur][r * 64 + qs * 8]);
            }
        }
#pragma unroll
        for (int kc = 0; kc < 2; ++kc)
#pragma unroll
            for (int mi = 0; mi < 2; ++mi)
#pragma unroll
                for (int ni = 0; ni < 2; ++ni)
                    acc[mi][ni] = __builtin_amdgcn_mfma_f32_16x16x32_bf16(
                        af[kc][mi], bfr[kc][ni], acc[mi][ni], 0, 0, 0);
        cur ^= 1;
    }

    float cbv[2];
#pragma unroll
    for (int ni = 0; ni < 2; ++ni)
        cbv[ni] = (sel == 0) ? b_corr[n0 + wc + ni * 16 + lr] : 0.f;
#pragma unroll
    for (int mi = 0; mi < 2; ++mi)
#pragma unroll
        for (int ni = 0; ni < 2; ++ni) {
            const int m = m0 + wr + mi * 16 + ko * 4;
            const int n = n0 + wc + ni * 16 + lr;
#pragma unroll
            for (int rr = 0; rr < 4; ++rr)
                C[(size_t)(m + rr) * H + n] = f2bf(acc[mi][ni][rr] + cbv[ni]);
        }
}

// ---------------------------------------------------------------------------
// k_tail: grid 577 x 256  (corres reads bf16 hf/hs)
// ---------------------------------------------------------------------------
__global__ __launch_bounds__(256) void k_tail(
    const unsigned short* __restrict__ hfbh, const unsigned short* __restrict__ hsbh,
    const float* __restrict__ relh_part, const float* __restrict__ b_relh,
    const float* __restrict__ W_gc, const float* __restrict__ W_rj,
    const float* __restrict__ b_rj,
    float* __restrict__ cpart, float* __restrict__ out)
{
    __shared__ float hfT[96][34];   // 13 KB
    const int bid = blockIdx.x, tid = threadIdx.x;

    if (bid < 576) {
        const int s    = bid & 7;
        const int tile = bid >> 3;
        const int b   = tile / 18;
        const int rem = tile % 18;
        const int i0  = (rem / 6) * 64;
        const int j0  = (rem % 6) * 32;
        const int h0  = s * 96;
        const int tx = tid & 15, ty = tid >> 4;

        // stage hf [96 k][32 j] from bf16 (384 x 8-elem slots)
#pragma unroll
        for (int it = 0; it < 2; ++it) {
            const int slot = it * 256 + tid;
            if (slot < 384) {
                const int j = slot / 12, kg = slot % 12;
                const uint4 v = *(const uint4*)(hfbh + (size_t)(b * LL + j0 + j) * H + h0 + kg * 8);
                const unsigned short* pu = (const unsigned short*)&v;
#pragma unroll
                for (int c = 0; c < 8; ++c)
                    hfT[kg * 8 + c][j] = bf2f(pu[c]);
            }
        }
        __syncthreads();

        float acc[4][2] = {{0.f}};
        float hsr[4][8];
        const unsigned short* hsbase = hsbh + (size_t)(b * LL + i0 + ty * 4) * H + h0;

        for (int kb = 0; kb < 96; kb += 8) {
#pragma unroll
            for (int ii = 0; ii < 4; ++ii) {
                const uint4 v = *(const uint4*)(hsbase + (size_t)ii * H + kb);
                const unsigned short* pu = (const unsigned short*)&v;
#pragma unroll
                for (int c = 0; c < 8; ++c) hsr[ii][c] = bf2f(pu[c]);
            }
            const float4 wa = *(const float4*)(W_gc + h0 + kb);
            const float4 wb = *(const float4*)(W_gc + h0 + kb + 4);
            const float wreg[8] = {wa.x, wa.y, wa.z, wa.w, wb.x, wb.y, wb.z, wb.w};
#pragma unroll
            for (int k8 = 0; k8 < 8; ++k8) {
                const int kk = kb + k8;
                const float2 f2 = *(const float2*)&hfT[kk][tx * 2];
                const float w = wreg[k8];
#pragma unroll
                for (int ii = 0; ii < 4; ++ii) {
                    acc[ii][0] += fabsf(f2.x + hsr[ii][k8]) * w;
                    acc[ii][1] += fabsf(f2.y + hsr[ii][k8]) * w;
                }
            }
        }
#pragma unroll
        for (int ii = 0; ii < 4; ++ii) {
            *(float2*)(cpart + (size_t)s * 147456 + (size_t)b * 36864
                       + (size_t)(i0 + ty * 4 + ii) * LL + j0 + tx * 2) =
                make_float2(acc[ii][0], acc[ii][1]);
        }
    } else {
        // ---- relh reduce + stage1 GEMV ----
        float* relhS = &hfT[0][0];   // 1536 floats
        for (int i = tid; i < 4 * Hh; i += 256) {
            const int b = i / Hh, o = i % Hh;
            float s = b_relh[o];
#pragma unroll
            for (int kc = 0; kc < 8; ++kc)
                s += relh_part[(size_t)(kc * 4 + b) * Hh + o];
            relhS[i] = fmaxf(s, 0.f);
        }
        __syncthreads();
        if (tid < 96) {
            const int b = tid / RR, rj = tid % RR;
            float s = b_rj[rj];
            for (int k = 0; k < Hh; ++k)
                s += relhS[b * Hh + k] * W_rj[k * RR + rj];
            out[b * RR + rj] = s;
        }
    }
}

// ---------------------------------------------------------------------------
// k_merge: grid 162 x 256  (identical to R14)
// ---------------------------------------------------------------------------
__global__ __launch_bounds__(256) void k_merge(
    const float* __restrict__ cpart, const float* __restrict__ hfw_ws,
    const float* __restrict__ traw, const float* __restrict__ tb_ws,
    const float* __restrict__ bc_ws, const float* __restrict__ b_gc,
    float* __restrict__ out)
{
    const int bid = blockIdx.x, tid = threadIdx.x;

    if (bid < 144) {
        const int idx = bid * 256 + tid;
        const int b  = idx / 9216;
        const int rr = idx % 9216;
        const int i  = rr / 48;
        const int j4 = (rr % 48) * 4;
        const size_t off = (size_t)b * 36864 + (size_t)i * LL + j4;

        float4 p = make_float4(0.f, 0.f, 0.f, 0.f);
#pragma unroll
        for (int s = 0; s < 8; ++s) {
            const float4 v = *(const float4*)(cpart + (size_t)s * 147456 + off);
            p.x += v.x; p.y += v.y; p.z += v.z; p.w += v.w;
        }
        const float4 hw = *(const float4*)(hfw_ws + b * LL + j4);
        const float hs = hfw_ws[768 + b * LL + i];
        const float bc = bc_ws[0];
        const float bg = b_gc[0];

        float4 o;
        o.x = 0.5f * (p.x + hw.x + hs + bc) + bg;
        o.y = 0.5f * (p.y + hw.y + hs + bc) + bg;
        o.z = 0.5f * (p.z + hw.z + hs + bc) + bg;
        o.w = 0.5f * (p.w + hw.w + hs + bc) + bg;
        *(float4*)(out + 4704 + off) = o;
    } else {
        // ---- tag finalize ----
        const int idx = (bid - 144) * 256 + tid;   // 0..4607
        if (idx < 4608) {
            const int r = idx / 6, c = idx % 6;
            const int b = r / LL;
            const float v = traw[r * 6 + c] + tb_ws[b * 8 + c];
            if (c < 3) out[96 + r * 3 + c] = v;
            else       out[2400 + r * 3 + (c - 3)] = v;
        }
    }
}

extern "C" void kernel_launch(void* const* d_in, const int* in_sizes, int n_in,
                              void* d_out, int out_size, void* d_ws, size_t ws_size,
                              hipStream_t stream) {
    const float* emb    = (const float*)d_in[0];
    const int*   mask   = (const int*)d_in[1];
    const int*   trel   = (const int*)d_in[2];
    const float* W_relh = (const float*)d_in[3];
    const float* b_relh = (const float*)d_in[4];
    const float* W_rj   = (const float*)d_in[5];
    const float* b_rj   = (const float*)d_in[6];
    const float* W_corr = (const float*)d_in[7];
    const float* b_corr = (const float*)d_in[8];
    const float* W_gc   = (const float*)d_in[9];
    const float* b_gc   = (const float*)d_in[10];
    const float* relemb = (const float*)d_in[11];
    const float* W_tag  = (const float*)d_in[12];
    const float* b_tag  = (const float*)d_in[13];
    const float* W_sub  = (const float*)d_in[14];
    const float* b_sub  = (const float*)d_in[15];
    const float* W_obj  = (const float*)d_in[16];
    const float* b_obj  = (const float*)d_in[17];

    float* out = (float*)d_out;
    float* ws  = (float*)d_ws;
    unsigned short* hfbh = (unsigned short*)ws;    // HH bf16
    unsigned short* hsbh = hfbh + (size_t)HH;      // HH bf16
    unsigned short* embh = hsbh + (size_t)HH;      // HH bf16
    unsigned short* wct0 = embh + (size_t)HH;      // HH bf16
    unsigned short* wct1 = wct0 + (size_t)HH;      // HH bf16
    float* smalls    = (float*)(wct1 + (size_t)HH);
    float* part      = smalls;                     // 24576
    float* msum_part = part + 24576;               // 32
    float* W8_ws     = msum_part + 32;             // 6144
    float* V8_ws     = W8_ws + 8 * H;              // 6144
    float* relh_part = V8_ws + 8 * H;              // 12288
    float* hfw_ws    = relh_part + 32 * Hh;        // 1536
    float* traw      = hfw_ws + 1536;              // 4608
    float* tb_ws     = traw + 4608;                // 32
    float* cb_ws     = tb_ws + 32;                 // 8
    float* bc_ws     = cb_ws + 8;                  // 8
    float* cpart     = bc_ws + 8 + 120;            // 8*147456

    k_pre<<<1105, 256, 0, stream>>>(emb, mask, W_corr, W_tag, W_gc, b_corr,
                                    W_sub, b_sub, W_obj, b_obj, b_tag,
                                    part, msum_part, embh, wct0, wct1,
                                    W8_ws, V8_ws, cb_ws, bc_ws);
    k_main<<<674, 256, 0, stream>>>(embh, wct0, wct1, b_corr,
                                    W_relh, part, msum_part, trel, relemb,
                                    V8_ws, cb_ws, emb, W8_ws,
                                    hfbh, hsbh, relh_part, hfw_ws, traw, tb_ws);
    k_tail<<<577, 256, 0, stream>>>(hfbh, hsbh, relh_part, b_relh,
                                    W_gc, W_rj, b_rj, cpart, out);
    k_merge<<<162, 256, 0, stream>>>(cpart, hfw_ws, traw, tb_ws,
                                     bc_ws, b_gc, out);
}

// Round 16
// 45.863 us; speedup vs baseline: 1.1081x; 1.0198x over previous
//
#include <hip/hip_runtime.h>

#define H   768
#define Hh  384
#define LL  192
#define RR  24
#define HH  589824   // 768*768

typedef __attribute__((ext_vector_type(8))) short bf16x8;
typedef __attribute__((ext_vector_type(4))) float f32x4;

__device__ __forceinline__ unsigned short f2bf(float f) {
    unsigned int u = __float_as_uint(f);
    return (unsigned short)((u + 0x7FFF + ((u >> 16) & 1)) >> 16);  // RNE
}

__device__ __forceinline__ float bf2f(unsigned short u) {
    return __uint_as_float((unsigned int)u << 16);
}

__device__ __forceinline__ void gload16(const void* g, void* l) {
    __builtin_amdgcn_global_load_lds(
        (const __attribute__((address_space(1))) unsigned int*)g,
        (__attribute__((address_space(3))) unsigned int*)l, 16, 0, 0);
}

__device__ __forceinline__ float wred(float v) {
#pragma unroll
    for (int off = 1; off < 64; off <<= 1) v += __shfl_xor(v, off);
    return v;
}

// ---------------------------------------------------------------------------
// k_pre: grid 1105 x 256  (identical to R15)
// ---------------------------------------------------------------------------
__global__ __launch_bounds__(256) void k_pre(
    const float* __restrict__ emb, const int* __restrict__ mask,
    const float* __restrict__ W_corr, const float* __restrict__ W_tag,
    const float* __restrict__ W_gc, const float* __restrict__ b_corr,
    const float* __restrict__ W_sub, const float* __restrict__ b_sub,
    const float* __restrict__ W_obj, const float* __restrict__ b_obj,
    const float* __restrict__ b_tag,
    float* __restrict__ part, float* __restrict__ msum_part,
    unsigned short* __restrict__ embh,
    unsigned short* __restrict__ wct0, unsigned short* __restrict__ wct1,
    float* __restrict__ W8_ws, float* __restrict__ V8_ws,
    float* __restrict__ cb_ws, float* __restrict__ bc_ws)
{
    const int bid = blockIdx.x, tid = threadIdx.x;

    if (bid < 192) {
        __shared__ float4 red4[8][32];
        const int b   = bid / 48;
        const int rem = bid % 48;
        const int hc  = rem / 8;
        const int lc  = rem % 8;
        const int h0  = hc * 128;
        const int l0  = lc * 24;
        const int tx = tid & 31, ty = tid >> 5;

        float4 acc = make_float4(0.f, 0.f, 0.f, 0.f);
#pragma unroll
        for (int r = 0; r < 3; ++r) {
            const int l = l0 + r * 8 + ty;
            const float m = (float)mask[b * LL + l];
            const float4 v = *(const float4*)(emb + (size_t)(b * LL + l) * H + h0 + tx * 4);
            acc.x += v.x * m; acc.y += v.y * m; acc.z += v.z * m; acc.w += v.w * m;
        }
        red4[ty][tx] = acc;
        if (hc == 0 && tid == 0) {
            float s = 0.f;
            for (int l = l0; l < l0 + 24; ++l) s += (float)mask[b * LL + l];
            msum_part[b * 8 + lc] = s;
        }
        __syncthreads();
        if (tid < 32) {
            float4 s = red4[0][tid];
#pragma unroll
            for (int r = 1; r < 8; ++r) {
                s.x += red4[r][tid].x; s.y += red4[r][tid].y;
                s.z += red4[r][tid].z; s.w += red4[r][tid].w;
            }
            *(float4*)(part + (size_t)lc * 4 * H + (size_t)b * H + h0 + tid * 4) = s;
        }
        return;
    }

    if (bid < 336) {
        const size_t t = (size_t)(bid - 192) * 256 + tid;
        const float* s = emb + t * 16;
        union { unsigned short u[16]; uint4 v[2]; } pk;
#pragma unroll
        for (int q = 0; q < 4; ++q) {
            const float4 v = *(const float4*)(s + q * 4);
            pk.u[q * 4 + 0] = f2bf(v.x); pk.u[q * 4 + 1] = f2bf(v.y);
            pk.u[q * 4 + 2] = f2bf(v.z); pk.u[q * 4 + 3] = f2bf(v.w);
        }
        *(uint4*)(embh + t * 16)     = pk.v[0];
        *(uint4*)(embh + t * 16 + 8) = pk.v[1];
        return;
    }

    if (bid < 912) {
        const int local = bid - 336;          // 0..575
        const int m  = local / 288;
        const int r2 = local % 288;
        const int ko = r2 / 3, nb = r2 % 3;
        const int n  = nb * 256 + tid;
        const float* src = (m == 0) ? W_corr : W_corr + HH;
        unsigned short* dst = (m == 0) ? wct0 : wct1;
        union { unsigned short u[8]; uint4 v; } pk;
#pragma unroll
        for (int q = 0; q < 8; ++q)
            pk.u[q] = f2bf(src[(size_t)(ko * 8 + q) * H + n]);
        *(uint4*)(dst + (size_t)n * H + ko * 8) = pk.v;
        return;
    }

    if (bid < 1104) {
        // ---- W8/V8 build: wave per k ----
        const int wave = tid >> 6, lane = tid & 63;
        const int k = (bid - 912) * 4 + wave;
        const float* rc0 = W_corr + (size_t)k * H;
        const float* rc1 = W_corr + (size_t)HH + (size_t)k * H;
        const float* rtl = W_tag + (size_t)k * H;
        const float* rth = W_tag + (size_t)(H + k) * H;
        float u0 = 0.f, u1 = 0.f;
        float wsv[3] = {0, 0, 0}, wov[3] = {0, 0, 0};
        float vsv[3] = {0, 0, 0}, vov[3] = {0, 0, 0};
#pragma unroll
        for (int it = 0; it < 3; ++it) {
            const int h = lane * 4 + it * 256;
            const float4 c0 = *(const float4*)(rc0 + h);
            const float4 c1 = *(const float4*)(rc1 + h);
            const float4 tl = *(const float4*)(rtl + h);
            const float4 th = *(const float4*)(rth + h);
            const float4 g  = *(const float4*)(W_gc + h);
            float su[12], ob[12];
            *(float4*)&su[0] = *(const float4*)(W_sub + h * 3);
            *(float4*)&su[4] = *(const float4*)(W_sub + h * 3 + 4);
            *(float4*)&su[8] = *(const float4*)(W_sub + h * 3 + 8);
            *(float4*)&ob[0] = *(const float4*)(W_obj + h * 3);
            *(float4*)&ob[4] = *(const float4*)(W_obj + h * 3 + 4);
            *(float4*)&ob[8] = *(const float4*)(W_obj + h * 3 + 8);
            u0 += c0.x * g.x + c0.y * g.y + c0.z * g.z + c0.w * g.w;
            u1 += c1.x * g.x + c1.y * g.y + c1.z * g.z + c1.w * g.w;
            const float t4[4] = {th.x, th.y, th.z, th.w};
            const float l4[4] = {tl.x, tl.y, tl.z, tl.w};
#pragma unroll
            for (int d = 0; d < 4; ++d)
#pragma unroll
                for (int c = 0; c < 3; ++c) {
                    wsv[c] += t4[d] * su[d * 3 + c];
                    vsv[c] += l4[d] * su[d * 3 + c];
                    wov[c] += t4[d] * ob[d * 3 + c];
                    vov[c] += l4[d] * ob[d * 3 + c];
                }
        }
        u0 = wred(u0); u1 = wred(u1);
#pragma unroll
        for (int c = 0; c < 3; ++c) {
            wsv[c] = wred(wsv[c]); wov[c] = wred(wov[c]);
            vsv[c] = wred(vsv[c]); vov[c] = wred(vov[c]);
        }
        if (lane == 0) {
            *(float4*)(W8_ws + k * 8)     = make_float4(u0, u1, wsv[0], wsv[1]);
            *(float4*)(W8_ws + k * 8 + 4) = make_float4(wsv[2], wov[0], wov[1], wov[2]);
            *(float4*)(V8_ws + k * 8)     = make_float4(vsv[0], vsv[1], vsv[2], vov[0]);
            *(float4*)(V8_ws + k * 8 + 4) = make_float4(vov[1], vov[2], 0.f, 0.f);
        }
        return;
    }

    // ---- bid == 1104: cb + bc ----
    {
        const int wave = tid >> 6, lane = tid & 63;
        if (wave == 0) {
            float cs[3] = {0, 0, 0}, co[3] = {0, 0, 0};
#pragma unroll
            for (int it = 0; it < 3; ++it) {
                const int h = lane * 4 + it * 256;
                const float4 bt = *(const float4*)(b_tag + h);
                float su[12], ob[12];
                *(float4*)&su[0] = *(const float4*)(W_sub + h * 3);
                *(float4*)&su[4] = *(const float4*)(W_sub + h * 3 + 4);
                *(float4*)&su[8] = *(const float4*)(W_sub + h * 3 + 8);
                *(float4*)&ob[0] = *(const float4*)(W_obj + h * 3);
                *(float4*)&ob[4] = *(const float4*)(W_obj + h * 3 + 4);
                *(float4*)&ob[8] = *(const float4*)(W_obj + h * 3 + 8);
                const float b4[4] = {bt.x, bt.y, bt.z, bt.w};
#pragma unroll
                for (int d = 0; d < 4; ++d)
#pragma unroll
                    for (int c = 0; c < 3; ++c) {
                        cs[c] += b4[d] * su[d * 3 + c];
                        co[c] += b4[d] * ob[d * 3 + c];
                    }
            }
#pragma unroll
            for (int c = 0; c < 3; ++c) { cs[c] = wred(cs[c]); co[c] = wred(co[c]); }
            if (lane == 0) {
#pragma unroll
                for (int c = 0; c < 3; ++c) {
                    cb_ws[c]     = cs[c] + b_sub[c];
                    cb_ws[3 + c] = co[c] + b_obj[c];
                }
            }
        } else if (wave == 1) {
            float s = 0.f;
#pragma unroll
            for (int it = 0; it < 3; ++it) {
                const int h = lane * 4 + it * 256;
                const float4 bcv = *(const float4*)(b_corr + h);
                const float4 g   = *(const float4*)(W_gc + h);
                s += bcv.x * g.x + bcv.y * g.y + bcv.z * g.z + bcv.w * g.w;
            }
            s = wred(s);
            if (lane == 0) bc_ws[0] = s;
        }
    }
}

// ---------------------------------------------------------------------------
// k_main: grid 674 x 256  (identical to R15)
// ---------------------------------------------------------------------------
__global__ __launch_bounds__(256) void k_main(
    const unsigned short* __restrict__ embh, const unsigned short* __restrict__ wct0,
    const unsigned short* __restrict__ wct1, const float* __restrict__ b_corr,
    const float* __restrict__ W_relh, const float* __restrict__ part,
    const float* __restrict__ msum_part,
    const int* __restrict__ target_rel, const float* __restrict__ rel_emb,
    const float* __restrict__ V8_ws, const float* __restrict__ cb_ws,
    const float* __restrict__ emb, const float* __restrict__ W8_ws,
    unsigned short* __restrict__ hfbh, unsigned short* __restrict__ hsbh,
    float* __restrict__ relh_part, float* __restrict__ hfw_ws,
    float* __restrict__ traw, float* __restrict__ tb_ws)
{
    __shared__ unsigned short As[2][4096];
    __shared__ unsigned short Bs[2][4096];
    const int bid = blockIdx.x, tid = threadIdx.x;

    if (bid >= 288) {
        if (bid < 480) {
            float* red  = (float*)&As[0][0];   // 256 floats
            float* avgS = red + 256;           // 96 floats
            const int rb = bid - 288;
            const int kc = rb & 7;
            const int t2 = rb >> 3;
            const int b  = t2 / 6;
            const int o0 = (t2 % 6) * 64;
            const int tx = tid & 63, ty = tid >> 6;
            if (tid < 96) {
                const int h = kc * 96 + tid;
                float s = 0.f;
#pragma unroll
                for (int lc = 0; lc < 8; ++lc)
                    s += part[(size_t)lc * 4 * H + (size_t)b * H + h];
                float ms = 0.f;
#pragma unroll
                for (int lc = 0; lc < 8; ++lc) ms += msum_part[b * 8 + lc];
                avgS[tid] = s / ms;
            }
            __syncthreads();
            const int hl0 = ty * 24;
            float s = 0.f;
            for (int hh = 0; hh < 24; ++hh)
                s += avgS[hl0 + hh] *
                     W_relh[(size_t)(kc * 96 + hl0 + hh) * Hh + o0 + tx];
            red[ty * 64 + tx] = s;
            __syncthreads();
            if (ty == 0)
                relh_part[(size_t)(kc * 4 + b) * Hh + o0 + tx] =
                    red[tx] + red[64 + tx] + red[128 + tx] + red[192 + tx];
        } else if (bid < 673) {
            const int wave = tid >> 6, lane = tid & 63;
            const int r = (bid - 480) * 4 + wave;   // 0..771
            if (r < 768) {
                const float* er = emb + (size_t)r * H;
                float s0 = 0.f, s1 = 0.f;
                float t[6] = {0, 0, 0, 0, 0, 0};
#pragma unroll
                for (int it = 0; it < 12; ++it) {
                    const int h = lane + it * 64;
                    const float e = er[h];
                    const float4 a = *(const float4*)(W8_ws + h * 8);
                    const float4 v = *(const float4*)(W8_ws + h * 8 + 4);
                    s0 += e * a.x; s1 += e * a.y;
                    t[0] += e * a.z; t[1] += e * a.w; t[2] += e * v.x;
                    t[3] += e * v.y; t[4] += e * v.z; t[5] += e * v.w;
                }
                s0 = wred(s0); s1 = wred(s1);
#pragma unroll
                for (int c = 0; c < 6; ++c) t[c] = wred(t[c]);
                if (lane == 0) {
                    hfw_ws[r] = s0;
                    hfw_ws[768 + r] = s1;
#pragma unroll
                    for (int c = 0; c < 6; ++c) traw[r * 6 + c] = t[c];
                }
            }
        } else {
            const int b = tid >> 6, lane = tid & 63;
            const float* re = rel_emb + (size_t)target_rel[b] * H;
            float t[6] = {0, 0, 0, 0, 0, 0};
#pragma unroll
            for (int it = 0; it < 12; ++it) {
                const int k = lane + it * 64;
                const float rl = re[k];
                const float4 a = *(const float4*)(V8_ws + k * 8);
                const float4 v = *(const float4*)(V8_ws + k * 8 + 4);
                t[0] += rl * a.x; t[1] += rl * a.y; t[2] += rl * a.z;
                t[3] += rl * a.w; t[4] += rl * v.x; t[5] += rl * v.y;
            }
#pragma unroll
            for (int c = 0; c < 6; ++c) t[c] = wred(t[c]);
            if (lane == 0) {
#pragma unroll
                for (int c = 0; c < 6; ++c)
                    tb_ws[b * 8 + c] = t[c] + cb_ws[c];
            }
        }
        return;
    }

    // ------------------ MFMA GEMM (gload_lds staging, bf16 C) ------------------
    const int sel = bid / 144;
    const int tt  = bid % 144;
    const int mt = tt % 12, nt = tt / 12;
    const int m0 = mt * 64, n0 = nt * 64;
    const unsigned short* Bsrc = sel ? wct1 : wct0;
    unsigned short* C = sel ? hsbh : hfbh;

    const int wv = tid >> 6, ln = tid & 63;
    const int lr = ln & 15, ko = ln >> 4;
    const int wr = (wv >> 1) * 32, wc = (wv & 1) * 32;

    f32x4 acc[2][2];
#pragma unroll
    for (int mi = 0; mi < 2; ++mi)
#pragma unroll
        for (int ni = 0; ni < 2; ++ni)
            acc[mi][ni] = (f32x4){0.f, 0.f, 0.f, 0.f};

    auto stage = [&](int buf, int k0) {
#pragma unroll
        for (int it = 0; it < 2; ++it) {
            const int sbase = it * 256 + wv * 64;
            const int slot = sbase + ln;
            const int r = slot >> 3, c = slot & 7;
            const int cs = c ^ (r & 7);
            gload16(embh + (size_t)(m0 + r) * H + k0 + cs * 8, &As[buf][sbase * 8]);
            gload16(Bsrc + (size_t)(n0 + r) * H + k0 + cs * 8, &Bs[buf][sbase * 8]);
        }
    };

    stage(0, 0);
    int cur = 0;
    for (int ks = 0; ks < 12; ++ks) {
        __syncthreads();
        if (ks < 11) stage(cur ^ 1, (ks + 1) * 64);
        bf16x8 af[2][2], bfr[2][2];
#pragma unroll
        for (int mi = 0; mi < 2; ++mi) {
            const int r = wr + mi * 16 + lr;
#pragma unroll
            for (int kc = 0; kc < 2; ++kc) {
                const int qs = (kc * 4 + ko) ^ (r & 7);
                af[kc][mi] = *(const bf16x8*)(&As[cur][r * 64 + qs * 8]);
            }
        }
#pragma unroll
        for (int ni = 0; ni < 2; ++ni) {
            const int r = wc + ni * 16 + lr;
#pragma unroll
            for (int kc = 0; kc < 2; ++kc) {
                const int qs = (kc * 4 + ko) ^ (r & 7);
                bfr[kc][ni] = *(const bf16x8*)(&Bs[cur][r * 64 + qs * 8]);
            }
        }
#pragma unroll
        for (int kc = 0; kc < 2; ++kc)
#pragma unroll
            for (int mi = 0; mi < 2; ++mi)
#pragma unroll
                for (int ni = 0; ni < 2; ++ni)
                    acc[mi][ni] = __builtin_amdgcn_mfma_f32_16x16x32_bf16(
                        af[kc][mi], bfr[kc][ni], acc[mi][ni], 0, 0, 0);
        cur ^= 1;
    }

    float cbv[2];
#pragma unroll
    for (int ni = 0; ni < 2; ++ni)
        cbv[ni] = (sel == 0) ? b_corr[n0 + wc + ni * 16 + lr] : 0.f;
#pragma unroll
    for (int mi = 0; mi < 2; ++mi)
#pragma unroll
        for (int ni = 0; ni < 2; ++ni) {
            const int m = m0 + wr + mi * 16 + ko * 4;
            const int n = n0 + wc + ni * 16 + lr;
#pragma unroll
            for (int rr = 0; rr < 4; ++rr)
                C[(size_t)(m + rr) * H + n] = f2bf(acc[mi][ni][rr] + cbv[ni]);
        }
}

// ---------------------------------------------------------------------------
// k_tail: grid 577 x 256  (corres reads bf16 hf/hs; writes bf16 cpart)
// ---------------------------------------------------------------------------
__global__ __launch_bounds__(256) void k_tail(
    const unsigned short* __restrict__ hfbh, const unsigned short* __restrict__ hsbh,
    const float* __restrict__ relh_part, const float* __restrict__ b_relh,
    const float* __restrict__ W_gc, const float* __restrict__ W_rj,
    const float* __restrict__ b_rj,
    unsigned short* __restrict__ cpart, float* __restrict__ out)
{
    __shared__ float hfT[96][34];   // 13 KB
    const int bid = blockIdx.x, tid = threadIdx.x;

    if (bid < 576) {
        const int s    = bid & 7;
        const int tile = bid >> 3;
        const int b   = tile / 18;
        const int rem = tile % 18;
        const int i0  = (rem / 6) * 64;
        const int j0  = (rem % 6) * 32;
        const int h0  = s * 96;
        const int tx = tid & 15, ty = tid >> 4;

#pragma unroll
        for (int it = 0; it < 2; ++it) {
            const int slot = it * 256 + tid;
            if (slot < 384) {
                const int j = slot / 12, kg = slot % 12;
                const uint4 v = *(const uint4*)(hfbh + (size_t)(b * LL + j0 + j) * H + h0 + kg * 8);
                const unsigned short* pu = (const unsigned short*)&v;
#pragma unroll
                for (int c = 0; c < 8; ++c)
                    hfT[kg * 8 + c][j] = bf2f(pu[c]);
            }
        }
        __syncthreads();

        float acc[4][2] = {{0.f}};
        float hsr[4][8];
        const unsigned short* hsbase = hsbh + (size_t)(b * LL + i0 + ty * 4) * H + h0;

        for (int kb = 0; kb < 96; kb += 8) {
#pragma unroll
            for (int ii = 0; ii < 4; ++ii) {
                const uint4 v = *(const uint4*)(hsbase + (size_t)ii * H + kb);
                const unsigned short* pu = (const unsigned short*)&v;
#pragma unroll
                for (int c = 0; c < 8; ++c) hsr[ii][c] = bf2f(pu[c]);
            }
            const float4 wa = *(const float4*)(W_gc + h0 + kb);
            const float4 wb = *(const float4*)(W_gc + h0 + kb + 4);
            const float wreg[8] = {wa.x, wa.y, wa.z, wa.w, wb.x, wb.y, wb.z, wb.w};
#pragma unroll
            for (int k8 = 0; k8 < 8; ++k8) {
                const int kk = kb + k8;
                const float2 f2 = *(const float2*)&hfT[kk][tx * 2];
                const float w = wreg[k8];
#pragma unroll
                for (int ii = 0; ii < 4; ++ii) {
                    acc[ii][0] += fabsf(f2.x + hsr[ii][k8]) * w;
                    acc[ii][1] += fabsf(f2.y + hsr[ii][k8]) * w;
                }
            }
        }
#pragma unroll
        for (int ii = 0; ii < 4; ++ii) {
            const unsigned int pk = (unsigned int)f2bf(acc[ii][0])
                                  | ((unsigned int)f2bf(acc[ii][1]) << 16);
            *(unsigned int*)(cpart + (size_t)s * 147456 + (size_t)b * 36864
                             + (size_t)(i0 + ty * 4 + ii) * LL + j0 + tx * 2) = pk;
        }
    } else {
        // ---- relh reduce + stage1 GEMV ----
        float* relhS = &hfT[0][0];   // 1536 floats
        for (int i = tid; i < 4 * Hh; i += 256) {
            const int b = i / Hh, o = i % Hh;
            float s = b_relh[o];
#pragma unroll
            for (int kc = 0; kc < 8; ++kc)
                s += relh_part[(size_t)(kc * 4 + b) * Hh + o];
            relhS[i] = fmaxf(s, 0.f);
        }
        __syncthreads();
        if (tid < 96) {
            const int b = tid / RR, rj = tid % RR;
            float s = b_rj[rj];
            for (int k = 0; k < Hh; ++k)
                s += relhS[b * Hh + k] * W_rj[k * RR + rj];
            out[b * RR + rj] = s;
        }
    }
}

// ---------------------------------------------------------------------------
// k_merge: grid 162 x 256  (reads bf16 cpart)
// ---------------------------------------------------------------------------
__global__ __launch_bounds__(256) void k_merge(
    const unsigned short* __restrict__ cpart, const float* __restrict__ hfw_ws,
    const float* __restrict__ traw, const float* __restrict__ tb_ws,
    const float* __restrict__ bc_ws, const float* __restrict__ b_gc,
    float* __restrict__ out)
{
    const int bid = blockIdx.x, tid = threadIdx.x;

    if (bid < 144) {
        const int idx = bid * 256 + tid;
        const int b  = idx / 9216;
        const int rr = idx % 9216;
        const int i  = rr / 48;
        const int j4 = (rr % 48) * 4;
        const size_t off = (size_t)b * 36864 + (size_t)i * LL + j4;

        float4 p = make_float4(0.f, 0.f, 0.f, 0.f);
#pragma unroll
        for (int s = 0; s < 8; ++s) {
            const unsigned long long v =
                *(const unsigned long long*)(cpart + (size_t)s * 147456 + off);
            p.x += bf2f((unsigned short)(v));
            p.y += bf2f((unsigned short)(v >> 16));
            p.z += bf2f((unsigned short)(v >> 32));
            p.w += bf2f((unsigned short)(v >> 48));
        }
        const float4 hw = *(const float4*)(hfw_ws + b * LL + j4);
        const float hs = hfw_ws[768 + b * LL + i];
        const float bc = bc_ws[0];
        const float bg = b_gc[0];

        float4 o;
        o.x = 0.5f * (p.x + hw.x + hs + bc) + bg;
        o.y = 0.5f * (p.y + hw.y + hs + bc) + bg;
        o.z = 0.5f * (p.z + hw.z + hs + bc) + bg;
        o.w = 0.5f * (p.w + hw.w + hs + bc) + bg;
        *(float4*)(out + 4704 + off) = o;
    } else {
        // ---- tag finalize ----
        const int idx = (bid - 144) * 256 + tid;   // 0..4607
        if (idx < 4608) {
            const int r = idx / 6, c = idx % 6;
            const int b = r / LL;
            const float v = traw[r * 6 + c] + tb_ws[b * 8 + c];
            if (c < 3) out[96 + r * 3 + c] = v;
            else       out[2400 + r * 3 + (c - 3)] = v;
        }
    }
}

extern "C" void kernel_launch(void* const* d_in, const int* in_sizes, int n_in,
                              void* d_out, int out_size, void* d_ws, size_t ws_size,
                              hipStream_t stream) {
    const float* emb    = (const float*)d_in[0];
    const int*   mask   = (const int*)d_in[1];
    const int*   trel   = (const int*)d_in[2];
    const float* W_relh = (const float*)d_in[3];
    const float* b_relh = (const float*)d_in[4];
    const float* W_rj   = (const float*)d_in[5];
    const float* b_rj   = (const float*)d_in[6];
    const float* W_corr = (const float*)d_in[7];
    const float* b_corr = (const float*)d_in[8];
    const float* W_gc   = (const float*)d_in[9];
    const float* b_gc   = (const float*)d_in[10];
    const float* relemb = (const float*)d_in[11];
    const float* W_tag  = (const float*)d_in[12];
    const float* b_tag  = (const float*)d_in[13];
    const float* W_sub  = (const float*)d_in[14];
    const float* b_sub  = (const float*)d_in[15];
    const float* W_obj  = (const float*)d_in[16];
    const float* b_obj  = (const float*)d_in[17];

    float* out = (float*)d_out;
    float* ws  = (float*)d_ws;
    unsigned short* hfbh = (unsigned short*)ws;    // HH bf16
    unsigned short* hsbh = hfbh + (size_t)HH;      // HH bf16
    unsigned short* embh = hsbh + (size_t)HH;      // HH bf16
    unsigned short* wct0 = embh + (size_t)HH;      // HH bf16
    unsigned short* wct1 = wct0 + (size_t)HH;      // HH bf16
    unsigned short* cpart = wct1 + (size_t)HH;     // 8*147456 bf16
    float* smalls    = (float*)(cpart + (size_t)8 * 147456);
    float* part      = smalls;                     // 24576
    float* msum_part = part + 24576;               // 32
    float* W8_ws     = msum_part + 32;             // 6144
    float* V8_ws     = W8_ws + 8 * H;              // 6144
    float* relh_part = V8_ws + 8 * H;              // 12288
    float* hfw_ws    = relh_part + 32 * Hh;        // 1536
    float* traw      = hfw_ws + 1536;              // 4608
    float* tb_ws     = traw + 4608;                // 32
    float* cb_ws     = tb_ws + 32;                 // 8
    float* bc_ws     = cb_ws + 8;                  // 8

    k_pre<<<1105, 256, 0, stream>>>(emb, mask, W_corr, W_tag, W_gc, b_corr,
                                    W_sub, b_sub, W_obj, b_obj, b_tag,
                                    part, msum_part, embh, wct0, wct1,
                                    W8_ws, V8_ws, cb_ws, bc_ws);
    k_main<<<674, 256, 0, stream>>>(embh, wct0, wct1, b_corr,
                                    W_relh, part, msum_part, trel, relemb,
                                    V8_ws, cb_ws, emb, W8_ws,
                                    hfbh, hsbh, relh_part, hfw_ws, traw, tb_ws);
    k_tail<<<577, 256, 0, stream>>>(hfbh, hsbh, relh_part, b_relh,
                                    W_gc, W_rj, b_rj, cpart, out);
    k_merge<<<162, 256, 0, stream>>>(cpart, hfw_ws, traw, tb_ws,
                                     bc_ws, b_gc, out);
}